// Round 11
// baseline (615.814 us; speedup 1.0000x reference)
//
#include <hip/hip_runtime.h>

#define N_NODES 50000
#define E_EDGES 800000
#define E2 (E_EDGES + N_NODES)
#define HC 256
#define NHEAD 4
#define GG 128
#define DENSE 64
#define NCLS 2
#define BN_EPS 1e-5f
#define NEG_SLOPE 0.2f
#define NEG_BIG -1e30f

typedef __attribute__((ext_vector_type(8))) short bf16x8;
typedef __attribute__((ext_vector_type(4))) float f32x4;

__device__ __forceinline__ unsigned short f2bf(float f) {
    unsigned int u = __float_as_uint(f);
    u = (u + 0x7FFFu + ((u >> 16) & 1u)) >> 16;
    return (unsigned short)u;
}
__device__ __forceinline__ float bf2f(unsigned short h) {
    return __uint_as_float(((unsigned int)h) << 16);
}
__device__ __forceinline__ float lrelu(float e) {
    return (e >= 0.f) ? e : NEG_SLOPE * e;
}
// accumulate 8 bf16 (packed in uint4) * w into acc[8]; lo=shift, hi=mask (no cvt)
__device__ __forceinline__ void accum8(float acc[8], uint4 v, float w) {
    acc[0] = fmaf(w, __uint_as_float(v.x << 16), acc[0]);
    acc[1] = fmaf(w, __uint_as_float(v.x & 0xffff0000u), acc[1]);
    acc[2] = fmaf(w, __uint_as_float(v.y << 16), acc[2]);
    acc[3] = fmaf(w, __uint_as_float(v.y & 0xffff0000u), acc[3]);
    acc[4] = fmaf(w, __uint_as_float(v.z << 16), acc[4]);
    acc[5] = fmaf(w, __uint_as_float(v.z & 0xffff0000u), acc[5]);
    acc[6] = fmaf(w, __uint_as_float(v.w << 16), acc[6]);
    acc[7] = fmaf(w, __uint_as_float(v.w & 0xffff0000u), acc[7]);
}

// ---------------- pack 3x W [256,256] fp32 into MFMA b-fragment order, bf16 ----------------
__global__ __launch_bounds__(64) void pack_b_kernel(const float* __restrict__ W1,
                                                    const float* __restrict__ Wl,
                                                    unsigned short* __restrict__ Bpk) {
    int l = threadIdx.x;
    int mat = blockIdx.x >> 7;          // 0..2
    int g = blockIdx.x & 127;           // ks*16+ct
    const float* W = (mat == 0) ? W1 : Wl + (size_t)(mat - 1) * HC * HC;
    int ks = g >> 4, ct = g & 15;
    int col = ct * 16 + (l & 15);
    int k0 = ks * 32 + (l >> 4) * 8;
    unsigned short v[8];
#pragma unroll
    for (int j = 0; j < 8; ++j) v[j] = f2bf(W[(size_t)(k0 + j) * HC + col]);
    ushort4* q = reinterpret_cast<ushort4*>(Bpk + ((size_t)mat * 128 * 512) + ((size_t)g * 64 + l) * 8);
    q[0] = make_ushort4(v[0], v[1], v[2], v[3]);
    q[1] = make_ushort4(v[4], v[5], v[6], v[7]);
}

// ---------------- MFMA GEMM + optional fp32-A staging / BN-affine staging + fused es/ed ----------------
__global__ __launch_bounds__(256) void gemm_mfma_kernel(const unsigned short* __restrict__ A,
                                                        const float* __restrict__ A32,
                                                        const unsigned short* __restrict__ Bpk,
                                                        const float* __restrict__ prm,
                                                        const float* __restrict__ avs,
                                                        const float* __restrict__ avd,
                                                        unsigned short* __restrict__ C,
                                                        float* __restrict__ es,
                                                        float* __restrict__ ed, int M) {
    __shared__ unsigned short As[64 * 256];  // 32 KB, XOR-swizzled rows
    int tid = threadIdx.x;
    int lane = tid & 63, wid = tid >> 6;
    int row0 = blockIdx.x * 64;
#pragma unroll
    for (int i = 0; i < 8; ++i) {
        int idx = tid + i * 256;
        int row = idx >> 5, c16 = idx & 31;
        int grow = row0 + row;
        uint4 v = make_uint4(0u, 0u, 0u, 0u);
        if (A32) {
            if (grow < M) {
                const float4* p = reinterpret_cast<const float4*>(A32 + (size_t)grow * HC + c16 * 8);
                float4 a = p[0], b = p[1];
                v.x = (unsigned int)f2bf(a.x) | ((unsigned int)f2bf(a.y) << 16);
                v.y = (unsigned int)f2bf(a.z) | ((unsigned int)f2bf(a.w) << 16);
                v.z = (unsigned int)f2bf(b.x) | ((unsigned int)f2bf(b.y) << 16);
                v.w = (unsigned int)f2bf(b.z) | ((unsigned int)f2bf(b.w) << 16);
            }
        } else {
            if (grow < M) v = *reinterpret_cast<const uint4*>(A + (size_t)grow * HC + c16 * 8);
            if (prm) {
                int ch = c16 * 8;
                const float4 s0 = *reinterpret_cast<const float4*>(prm + ch);
                const float4 s1 = *reinterpret_cast<const float4*>(prm + ch + 4);
                const float4 t0 = *reinterpret_cast<const float4*>(prm + HC + ch);
                const float4 t1 = *reinterpret_cast<const float4*>(prm + HC + ch + 4);
                float f0 = fmaxf(fmaf(__uint_as_float(v.x << 16),          s0.x, t0.x), 0.f);
                float f1 = fmaxf(fmaf(__uint_as_float(v.x & 0xffff0000u),  s0.y, t0.y), 0.f);
                float f2 = fmaxf(fmaf(__uint_as_float(v.y << 16),          s0.z, t0.z), 0.f);
                float f3 = fmaxf(fmaf(__uint_as_float(v.y & 0xffff0000u),  s0.w, t0.w), 0.f);
                float f4 = fmaxf(fmaf(__uint_as_float(v.z << 16),          s1.x, t1.x), 0.f);
                float f5 = fmaxf(fmaf(__uint_as_float(v.z & 0xffff0000u),  s1.y, t1.y), 0.f);
                float f6 = fmaxf(fmaf(__uint_as_float(v.w << 16),          s1.z, t1.z), 0.f);
                float f7 = fmaxf(fmaf(__uint_as_float(v.w & 0xffff0000u),  s1.w, t1.w), 0.f);
                v.x = (unsigned int)f2bf(f0) | ((unsigned int)f2bf(f1) << 16);
                v.y = (unsigned int)f2bf(f2) | ((unsigned int)f2bf(f3) << 16);
                v.z = (unsigned int)f2bf(f4) | ((unsigned int)f2bf(f5) << 16);
                v.w = (unsigned int)f2bf(f6) | ((unsigned int)f2bf(f7) << 16);
            }
        }
        int byteoff = row * 512 + c16 * 16;
        byteoff ^= (row & 7) << 4;
        *reinterpret_cast<uint4*>((char*)As + byteoff) = v;
    }
    __syncthreads();

    f32x4 acc[16];
#pragma unroll
    for (int ct = 0; ct < 16; ++ct) acc[ct] = (f32x4){0.f, 0.f, 0.f, 0.f};

    int mrow = wid * 16 + (lane & 15);
#pragma unroll
    for (int ks = 0; ks < 8; ++ks) {
        int abyte = mrow * 512 + ks * 64 + (lane >> 4) * 16;
        abyte ^= (mrow & 7) << 4;
        bf16x8 a = *reinterpret_cast<const bf16x8*>((char*)As + abyte);
        const unsigned short* bp = Bpk + ((size_t)(ks * 16) * 512 + lane * 8);
#pragma unroll
        for (int ct = 0; ct < 16; ++ct) {
            bf16x8 b = *reinterpret_cast<const bf16x8*>(bp + (size_t)ct * 512);
            acc[ct] = __builtin_amdgcn_mfma_f32_16x16x32_bf16(a, b, acc[ct], 0, 0, 0);
        }
    }
    // C/D layout: col = lane&15, row = (lane>>4)*4 + r
    int crow0 = row0 + wid * 16 + (lane >> 4) * 4;
    int ccol = lane & 15;
#pragma unroll
    for (int ct = 0; ct < 16; ++ct) {
#pragma unroll
        for (int r = 0; r < 4; ++r) {
            int grow = crow0 + r;
            if (grow < M) C[(size_t)grow * HC + ct * 16 + ccol] = f2bf(acc[ct][r]);
        }
    }
    // fused es/ed: head h covers ct in [4h,4h+4); 16-lane butterfly reduce per row
    float avsv[16], advv[16];
#pragma unroll
    for (int ct = 0; ct < 16; ++ct) {
        avsv[ct] = avs[ct * 16 + ccol];
        advv[ct] = avd[ct * 16 + ccol];
    }
#pragma unroll
    for (int r = 0; r < 4; ++r) {
        int grow = crow0 + r;
        float p0 = acc[0][r]*avsv[0] + acc[1][r]*avsv[1] + acc[2][r]*avsv[2] + acc[3][r]*avsv[3];
        float p1 = acc[4][r]*avsv[4] + acc[5][r]*avsv[5] + acc[6][r]*avsv[6] + acc[7][r]*avsv[7];
        float p2 = acc[8][r]*avsv[8] + acc[9][r]*avsv[9] + acc[10][r]*avsv[10] + acc[11][r]*avsv[11];
        float p3 = acc[12][r]*avsv[12] + acc[13][r]*avsv[13] + acc[14][r]*avsv[14] + acc[15][r]*avsv[15];
        float q0 = acc[0][r]*advv[0] + acc[1][r]*advv[1] + acc[2][r]*advv[2] + acc[3][r]*advv[3];
        float q1 = acc[4][r]*advv[4] + acc[5][r]*advv[5] + acc[6][r]*advv[6] + acc[7][r]*advv[7];
        float q2 = acc[8][r]*advv[8] + acc[9][r]*advv[9] + acc[10][r]*advv[10] + acc[11][r]*advv[11];
        float q3 = acc[12][r]*advv[12] + acc[13][r]*advv[13] + acc[14][r]*advv[14] + acc[15][r]*advv[15];
#pragma unroll
        for (int off = 1; off < 16; off <<= 1) {
            p0 += __shfl_xor(p0, off, 64); p1 += __shfl_xor(p1, off, 64);
            p2 += __shfl_xor(p2, off, 64); p3 += __shfl_xor(p3, off, 64);
            q0 += __shfl_xor(q0, off, 64); q1 += __shfl_xor(q1, off, 64);
            q2 += __shfl_xor(q2, off, 64); q3 += __shfl_xor(q3, off, 64);
        }
        if (ccol == 0 && grow < M) {
            *reinterpret_cast<float4*>(es + (size_t)grow * 4) = make_float4(p0, p1, p2, p3);
            *reinterpret_cast<float4*>(ed + (size_t)grow * 4) = make_float4(q0, q1, q2, q3);
        }
    }
}

// ---------------- CSR build ----------------
__global__ void init_deg_kernel(int* __restrict__ deg) {
    int i = blockIdx.x * blockDim.x + threadIdx.x;
    if (i < N_NODES) deg[i] = 1;  // self loop
}
__global__ void count_edges_kernel(const int* __restrict__ dst, int* __restrict__ deg) {
    int i = blockIdx.x * blockDim.x + threadIdx.x;
    if (i < E_EDGES) atomicAdd(&deg[dst[i]], 1);
}
__global__ __launch_bounds__(1024) void scan1_kernel(const int* __restrict__ deg,
                                                     int* __restrict__ rs, int* __restrict__ bsum) {
    __shared__ int wsum[16];
    int t = threadIdx.x, lane = t & 63, wid = t >> 6;
    int i = blockIdx.x * 1024 + t;
    int v = (i < N_NODES) ? deg[i] : 0;
    int x = v;
#pragma unroll
    for (int off = 1; off < 64; off <<= 1) {
        int y = __shfl_up(x, off, 64);
        if (lane >= off) x += y;
    }
    if (lane == 63) wsum[wid] = x;
    __syncthreads();
    if (wid == 0) {
        int s = (lane < 16) ? wsum[lane] : 0;
#pragma unroll
        for (int off = 1; off < 16; off <<= 1) {
            int y = __shfl_up(s, off, 64);
            if (lane >= off) s += y;
        }
        if (lane < 16) wsum[lane] = s;
    }
    __syncthreads();
    int woff = wid ? wsum[wid - 1] : 0;
    if (i <= N_NODES) rs[i] = woff + x - v;
    if (t == 1023) bsum[blockIdx.x] = wsum[15];
}
__global__ void scan2_kernel(int* __restrict__ bsum, int nb) {
    int l = threadIdx.x;
    int v = (l < nb) ? bsum[l] : 0;
    int x = v;
#pragma unroll
    for (int off = 1; off < 64; off <<= 1) {
        int y = __shfl_up(x, off, 64);
        if (l >= off) x += y;
    }
    if (l < nb) bsum[l] = x - v;
}
// scan3 + self-loop scatter fused: csr[v] = i (self loop first), cursor = v+1
__global__ void scan3_kernel(int* __restrict__ rs, const int* __restrict__ bsum,
                             int* __restrict__ cursor, int* __restrict__ csr) {
    int i = blockIdx.x * blockDim.x + threadIdx.x;
    if (i <= N_NODES) {
        int v = rs[i] + bsum[i >> 10];
        rs[i] = v;
        if (i < N_NODES) {
            csr[v] = i;
            cursor[i] = v + 1;
        }
    }
}
__global__ void scatter_edges_kernel(const int* __restrict__ src, const int* __restrict__ dst,
                                     int* __restrict__ cursor, int* __restrict__ csr) {
    int i = blockIdx.x * blockDim.x + threadIdx.x;
    if (i < E_EDGES) {
        int pos = atomicAdd(&cursor[dst[i]], 1);
        csr[pos] = src[i];
    }
}

// ---------------- softmax prep: (m,s) pass stashes e; rescale pass is streaming ----------------
__global__ __launch_bounds__(256) void smprep_kernel(const float* __restrict__ es,
                                                     const float* __restrict__ ed,
                                                     const int* __restrict__ rs,
                                                     const int* __restrict__ csr,
                                                     float* __restrict__ alpha) {
    int tid = threadIdx.x;
    int lane = tid & 63, wid = tid >> 6;
    int node = blockIdx.x * 4 + wid;
    if (node >= N_NODES) return;
    int head = lane >> 4, slot = lane & 15;
    float edn = ed[node * NHEAD + head];
    int beg = rs[node], end = rs[node + 1];
    // finite sentinel: -inf would produce NaN on empty-slot merges (deg<16 common)
    float m = NEG_BIG, s = 0.f;
    for (int i = beg + slot; i < end; i += 16) {
        float e = lrelu(es[csr[i] * NHEAD + head] + edn);
        alpha[(size_t)i * NHEAD + head] = e;   // stash for pass 2 (coalesced)
        float mn = fmaxf(m, e);
        s = s * __expf(m - mn) + __expf(e - mn);
        m = mn;
    }
#pragma unroll
    for (int off = 1; off < 16; off <<= 1) {  // merge within head group (low 4 bits)
        float mo = __shfl_xor(m, off, 64);
        float so = __shfl_xor(s, off, 64);
        float mn = fmaxf(m, mo);
        s = s * __expf(m - mn) + so * __expf(mo - mn);
        m = mn;
    }
    float inv = 1.f / (s + 1e-16f);
    for (int i = beg + slot; i < end; i += 16) {
        float e = alpha[(size_t)i * NHEAD + head];
        alpha[(size_t)i * NHEAD + head] = __expf(e - m) * inv;
    }
}

// ---------------- GAT aggregation: 2 nodes/wave, 16B/lane, unroll 4 ----------------
__global__ __launch_bounds__(256) void gat_agg_kernel(const unsigned short* __restrict__ hlin,
                                                      const float* __restrict__ alpha,
                                                      const int* __restrict__ rs,
                                                      const int* __restrict__ csr,
                                                      const float* __restrict__ bias,
                                                      unsigned short* __restrict__ out, int do_relu) {
    int tid = threadIdx.x;
    int lane = tid & 63, wid = tid >> 6;
    int node = blockIdx.x * 8 + wid * 2 + (lane >> 5);
    int hl = lane & 31;
    int ch0 = hl * 8;          // 8 channels per lane (16B)
    int head = hl >> 3;
    bool valid = node < N_NODES;
    int beg = valid ? rs[node] : 0;
    int end = valid ? rs[node + 1] : 0;
    float acc[8] = {};
    int idx = beg;
    for (; idx + 4 <= end; idx += 4) {
        int s0 = csr[idx], s1 = csr[idx + 1], s2 = csr[idx + 2], s3 = csr[idx + 3];
        float p0 = alpha[(size_t)idx * NHEAD + head];
        float p1 = alpha[(size_t)(idx + 1) * NHEAD + head];
        float p2 = alpha[(size_t)(idx + 2) * NHEAD + head];
        float p3 = alpha[(size_t)(idx + 3) * NHEAD + head];
        uint4 v0 = *reinterpret_cast<const uint4*>(hlin + (size_t)s0 * HC + ch0);
        uint4 v1 = *reinterpret_cast<const uint4*>(hlin + (size_t)s1 * HC + ch0);
        uint4 v2 = *reinterpret_cast<const uint4*>(hlin + (size_t)s2 * HC + ch0);
        uint4 v3 = *reinterpret_cast<const uint4*>(hlin + (size_t)s3 * HC + ch0);
        accum8(acc, v0, p0);
        accum8(acc, v1, p1);
        accum8(acc, v2, p2);
        accum8(acc, v3, p3);
    }
    for (; idx < end; ++idx) {
        int s0 = csr[idx];
        float p0 = alpha[(size_t)idx * NHEAD + head];
        uint4 v0 = *reinterpret_cast<const uint4*>(hlin + (size_t)s0 * HC + ch0);
        accum8(acc, v0, p0);
    }
    if (!valid) return;
    const float4 bva = *reinterpret_cast<const float4*>(bias + ch0);
    const float4 bvb = *reinterpret_cast<const float4*>(bias + ch0 + 4);
    float o[8];
    o[0] = acc[0] + bva.x; o[1] = acc[1] + bva.y; o[2] = acc[2] + bva.z; o[3] = acc[3] + bva.w;
    o[4] = acc[4] + bvb.x; o[5] = acc[5] + bvb.y; o[6] = acc[6] + bvb.z; o[7] = acc[7] + bvb.w;
    if (do_relu) {
#pragma unroll
        for (int j = 0; j < 8; ++j) o[j] = fmaxf(o[j], 0.f);
    }
    uint4 w;
    w.x = (unsigned int)f2bf(o[0]) | ((unsigned int)f2bf(o[1]) << 16);
    w.y = (unsigned int)f2bf(o[2]) | ((unsigned int)f2bf(o[3]) << 16);
    w.z = (unsigned int)f2bf(o[4]) | ((unsigned int)f2bf(o[5]) << 16);
    w.w = (unsigned int)f2bf(o[6]) | ((unsigned int)f2bf(o[7]) << 16);
    *reinterpret_cast<uint4*>(out + (size_t)node * HC + ch0) = w;
}

// ---------------- BatchNorm stats: 8 row-threads x 32 ch-threads, 16B loads ----------------
#define BN_RPB 49
__global__ __launch_bounds__(256) void bn_stats_kernel(const unsigned short* __restrict__ x,
                                                       float* __restrict__ sums) {
    __shared__ float lds[8][512];
    int tid = threadIdx.x;
    int c = tid & 31;   // channels c*8 .. c*8+7
    int rt = tid >> 5;  // 0..7
    int r0 = blockIdx.x * BN_RPB;
    int r1 = min(N_NODES, r0 + BN_RPB);
    int ch = c * 8;
    float s[8] = {}, s2[8] = {};
    for (int r = r0 + rt; r < r1; r += 8) {
        const ushort4* p = reinterpret_cast<const ushort4*>(x + (size_t)r * HC + ch);
        ushort4 va = p[0], vb = p[1];
        unsigned short in[8] = {va.x, va.y, va.z, va.w, vb.x, vb.y, vb.z, vb.w};
#pragma unroll
        for (int j = 0; j < 8; ++j) {
            float v = bf2f(in[j]);
            s[j] += v; s2[j] += v * v;
        }
    }
#pragma unroll
    for (int j = 0; j < 8; ++j) {
        lds[rt][ch + j] = s[j];
        lds[rt][256 + ch + j] = s2[j];
    }
    __syncthreads();
#pragma unroll
    for (int e = tid; e < 512; e += 256) {
        float v = 0.f;
#pragma unroll
        for (int r = 0; r < 8; ++r) v += lds[r][e];
        atomicAdd(&sums[e], v);
    }
}
__global__ void bn_finalize_kernel(const float* __restrict__ sums, const float* __restrict__ g,
                                   const float* __restrict__ b, float* __restrict__ prm) {
    int t = threadIdx.x;  // 256
    float mean = sums[t] / (float)N_NODES;
    float var = sums[HC + t] / (float)N_NODES - mean * mean;
    var = fmaxf(var, 0.f);
    float scale = g[t] * rsqrtf(var + BN_EPS);
    prm[t] = scale;
    prm[HC + t] = b[t] - mean * scale;
}

// ---------------- pooling (fused BN affine + ReLU on h2) ----------------
#define POOL_RPB 32
__global__ __launch_bounds__(256) void pool_kernel(const unsigned short* __restrict__ h,
                                                   const float* __restrict__ prm,
                                                   const int* __restrict__ batch,
                                                   float* __restrict__ psum) {
    int tid = threadIdx.x;
    int ct = tid & 63;   // channels ct*4 .. ct*4+3
    int rt = tid >> 6;   // 0..3
    int r0 = blockIdx.x * POOL_RPB;
    int r1 = min(N_NODES, r0 + POOL_RPB);
    int ch = ct * 4;
    const float4 sc = *reinterpret_cast<const float4*>(prm + ch);
    const float4 sh = *reinterpret_cast<const float4*>(prm + HC + ch);
    float a0 = 0.f, a1 = 0.f, a2 = 0.f, a3 = 0.f;
    int gcur = -1;
    for (int r = r0 + rt; r < r1; r += 4) {
        int g = batch[r];
        if (g != gcur) {
            if (gcur >= 0) {
                atomicAdd(&psum[gcur * HC + ch + 0], a0);
                atomicAdd(&psum[gcur * HC + ch + 1], a1);
                atomicAdd(&psum[gcur * HC + ch + 2], a2);
                atomicAdd(&psum[gcur * HC + ch + 3], a3);
            }
            a0 = a1 = a2 = a3 = 0.f; gcur = g;
        }
        ushort4 hv = *reinterpret_cast<const ushort4*>(h + (size_t)r * HC + ch);
        a0 += fmaxf(fmaf(bf2f(hv.x), sc.x, sh.x), 0.f);
        a1 += fmaxf(fmaf(bf2f(hv.y), sc.y, sh.y), 0.f);
        a2 += fmaxf(fmaf(bf2f(hv.z), sc.z, sh.z), 0.f);
        a3 += fmaxf(fmaf(bf2f(hv.w), sc.w, sh.w), 0.f);
    }
    if (gcur >= 0) {
        atomicAdd(&psum[gcur * HC + ch + 0], a0);
        atomicAdd(&psum[gcur * HC + ch + 1], a1);
        atomicAdd(&psum[gcur * HC + ch + 2], a2);
        atomicAdd(&psum[gcur * HC + ch + 3], a3);
    }
}
// pool_fin with inline binary-search counts (batch sorted)
__global__ void pool_fin_kernel(const float* __restrict__ psum, const int* __restrict__ batch,
                                float* __restrict__ pooled) {
    int g = blockIdx.x, t = threadIdx.x;
    int lo = 0, hi = N_NODES;
    while (lo < hi) { int mid = (lo + hi) >> 1; if (batch[mid] <= g) lo = mid + 1; else hi = mid; }
    int lo2 = 0, hi2 = N_NODES;
    while (lo2 < hi2) { int mid = (lo2 + hi2) >> 1; if (batch[mid] <= g - 1) lo2 = mid + 1; else hi2 = mid; }
    float cf = fmaxf((float)(lo - lo2), 1.f);
    pooled[g * HC + t] = psum[g * HC + t] / cf;
}

// ---------------- head ----------------
__global__ __launch_bounds__(256) void bn_head_kernel(const float* __restrict__ pooled,
                                                      const float* __restrict__ g,
                                                      const float* __restrict__ b,
                                                      float* __restrict__ z) {
    int t = threadIdx.x;  // channel
    float s = 0.f, s2 = 0.f;
    for (int r = 0; r < GG; ++r) {
        float v = pooled[r * HC + t];
        s += v; s2 += v * v;
    }
    float mean = s / (float)GG;
    float var = fmaxf(s2 / (float)GG - mean * mean, 0.f);
    float scale = g[t] * rsqrtf(var + BN_EPS);
    float shift = b[t] - mean * scale;
    for (int r = 0; r < GG; ++r)
        z[r * HC + t] = pooled[r * HC + t] * scale + shift;
}
__global__ __launch_bounds__(64) void lin_relu_kernel(const float* __restrict__ X,
                                                      const float* __restrict__ W,
                                                      const float* __restrict__ b,
                                                      float* __restrict__ Y, int K) {
    __shared__ float xr[256];
    int r = blockIdx.x, t = threadIdx.x;
    for (int k = t; k < K; k += 64) xr[k] = X[r * K + k];
    __syncthreads();
    float a = b[t];
    for (int k = 0; k < K; ++k) a += xr[k] * W[k * DENSE + t];
    Y[r * DENSE + t] = fmaxf(a, 0.f);
}
__global__ __launch_bounds__(128) void lin3_softmax_kernel(const float* __restrict__ X,
                                                           const float* __restrict__ W,
                                                           const float* __restrict__ b,
                                                           float* __restrict__ out) {
    int r = threadIdx.x;  // 128 rows
    const float* xr = X + r * DENSE;
    float o0 = b[0], o1 = b[1];
    for (int k = 0; k < DENSE; ++k) {
        o0 += xr[k] * W[k * NCLS + 0];
        o1 += xr[k] * W[k * NCLS + 1];
    }
    o0 = fmaxf(o0, 0.f); o1 = fmaxf(o1, 0.f);
    float mx = fmaxf(o0, o1);
    float e0 = __expf(o0 - mx), e1 = __expf(o1 - mx);
    float inv = 1.f / (e0 + e1);
    out[r * NCLS + 0] = e0 * inv;
    out[r * NCLS + 1] = e1 * inv;
}

extern "C" void kernel_launch(void* const* d_in, const int* in_sizes, int n_in,
                              void* d_out, int out_size, void* d_ws, size_t ws_size,
                              hipStream_t stream) {
    const float* x     = (const float*)d_in[0];
    const int*   ei    = (const int*)d_in[1];
    const int*   srcp  = ei;
    const int*   dstp  = ei + E_EDGES;
    const int*   batch = (const int*)d_in[2];
    const float* W1    = (const float*)d_in[3];
    const float* as1   = (const float*)d_in[4];
    const float* ad1   = (const float*)d_in[5];
    const float* b1    = (const float*)d_in[6];
    const float* Wl    = (const float*)d_in[7];
    const float* asl   = (const float*)d_in[8];
    const float* adl   = (const float*)d_in[9];
    const float* bl    = (const float*)d_in[10];
    const float* bng   = (const float*)d_in[11];
    const float* bnb   = (const float*)d_in[12];
    const float* bn1g  = (const float*)d_in[13];
    const float* bn1b  = (const float*)d_in[14];
    const float* l1W   = (const float*)d_in[15];
    const float* l1b   = (const float*)d_in[16];
    const float* l2W   = (const float*)d_in[17];
    const float* l2b   = (const float*)d_in[18];
    const float* l3W   = (const float*)d_in[19];
    const float* l3b   = (const float*)d_in[20];

    float* outp   = (float*)d_out;            // [128,2]
    float* pooled = outp + GG * NCLS;         // [128,256]

    char* w = (char*)d_ws;
    auto alloc = [&](size_t bytes) -> void* {
        void* p = (void*)w;
        w += (bytes + 255) & ~(size_t)255;
        return p;
    };
    unsigned short* h0  = (unsigned short*)alloc(sizeof(short) * (size_t)N_NODES * HC);
    unsigned short* h1  = (unsigned short*)alloc(sizeof(short) * (size_t)N_NODES * HC);
    unsigned short* h2  = (unsigned short*)alloc(sizeof(short) * (size_t)N_NODES * HC);
    unsigned short* Bpk = (unsigned short*)alloc(sizeof(short) * 3 * 128 * 64 * 8);
    float* es     = (float*)alloc(sizeof(float) * (size_t)N_NODES * NHEAD);
    float* ed     = (float*)alloc(sizeof(float) * (size_t)N_NODES * NHEAD);
    float* alpha  = (float*)alloc(sizeof(float) * (size_t)E2 * NHEAD);
    int*   rs     = (int*)alloc(sizeof(int) * (N_NODES + 1));
    int*   deg    = (int*)alloc(sizeof(int) * N_NODES);  // reused as cursor
    int*   csr    = (int*)alloc(sizeof(int) * E2);
    int*   bsum   = (int*)alloc(sizeof(int) * 64);
    float* bnsums = (float*)alloc(sizeof(float) * 2 * HC);
    float* bnprm  = (float*)alloc(sizeof(float) * 2 * HC);
    float* psum   = (float*)alloc(sizeof(float) * GG * HC);
    float* z0     = (float*)alloc(sizeof(float) * GG * HC);
    float* z1     = (float*)alloc(sizeof(float) * GG * DENSE);
    float* z2     = (float*)alloc(sizeof(float) * GG * DENSE);

    const int nblk_nodes = (N_NODES + 255) / 256;
    const int nblk_edges = (E_EDGES + 255) / 256;
    const int nblk_wave4 = (N_NODES + 3) / 4;
    const int nblk_wave8 = (N_NODES + 7) / 8;            // 6250 (2 nodes/wave)
    const int nscan = (N_NODES + 1023) / 1024;           // 49
    const int nblk_bn   = (N_NODES + BN_RPB - 1) / BN_RPB;     // 1021
    const int nblk_pool = (N_NODES + POOL_RPB - 1) / POOL_RPB; // 1563

    // ---- pack weights (3 matrices, one dispatch) ----
    pack_b_kernel<<<384, 64, 0, stream>>>(W1, Wl, Bpk);

    // ---- CSR build ----
    init_deg_kernel<<<nblk_nodes, 256, 0, stream>>>(deg);
    count_edges_kernel<<<nblk_edges, 256, 0, stream>>>(dstp, deg);
    scan1_kernel<<<nscan, 1024, 0, stream>>>(deg, rs, bsum);
    scan2_kernel<<<1, 64, 0, stream>>>(bsum, nscan);
    scan3_kernel<<<(N_NODES + 256) / 256, 256, 0, stream>>>(rs, bsum, deg, csr);
    scatter_edges_kernel<<<nblk_edges, 256, 0, stream>>>(srcp, dstp, deg, csr);

    const int ggrid = (N_NODES + 63) / 64;

    // ---- layer 1: gemm reads fp32 x directly; h0 = relu(gat(x)) ----
    gemm_mfma_kernel<<<ggrid, 256, 0, stream>>>(nullptr, x, Bpk, nullptr, as1, ad1, h1, es, ed, N_NODES);
    smprep_kernel<<<nblk_wave4, 256, 0, stream>>>(es, ed, rs, csr, alpha);
    gat_agg_kernel<<<nblk_wave8, 256, 0, stream>>>(h1, alpha, rs, csr, b1, h0, 1);

    // ---- inner layer 0 ----
    gemm_mfma_kernel<<<ggrid, 256, 0, stream>>>(h0, nullptr, Bpk + 128 * 512, nullptr, asl, adl, h1, es, ed, N_NODES);
    smprep_kernel<<<nblk_wave4, 256, 0, stream>>>(es, ed, rs, csr, alpha);
    gat_agg_kernel<<<nblk_wave8, 256, 0, stream>>>(h1, alpha, rs, csr, bl, h2, 0);
    hipMemsetAsync(bnsums, 0, sizeof(float) * 2 * HC, stream);
    bn_stats_kernel<<<nblk_bn, 256, 0, stream>>>(h2, bnsums);
    bn_finalize_kernel<<<1, 256, 0, stream>>>(bnsums, bng, bnb, bnprm);

    // ---- inner layer 1: gemm reads h2 with fused BN0 affine+relu ----
    gemm_mfma_kernel<<<ggrid, 256, 0, stream>>>(h2, nullptr, Bpk + 2 * 128 * 512, bnprm, asl + HC, adl + HC, h1, es, ed, N_NODES);
    smprep_kernel<<<nblk_wave4, 256, 0, stream>>>(es, ed, rs, csr, alpha);
    gat_agg_kernel<<<nblk_wave8, 256, 0, stream>>>(h1, alpha, rs, csr, bl + HC, h2, 0);
    hipMemsetAsync(bnsums, 0, sizeof(float) * 2 * HC, stream);
    bn_stats_kernel<<<nblk_bn, 256, 0, stream>>>(h2, bnsums);
    bn_finalize_kernel<<<1, 256, 0, stream>>>(bnsums, bng + HC, bnb + HC, bnprm);

    // ---- pooling (fused BN1 affine+relu) ----
    hipMemsetAsync(psum, 0, sizeof(float) * GG * HC, stream);
    pool_kernel<<<nblk_pool, 256, 0, stream>>>(h2, bnprm, batch, psum);
    pool_fin_kernel<<<GG, HC, 0, stream>>>(psum, batch, pooled);

    // ---- head ----
    bn_head_kernel<<<1, HC, 0, stream>>>(pooled, bn1g, bn1b, z0);
    lin_relu_kernel<<<GG, 64, 0, stream>>>(z0, l1W, l1b, z1, HC);
    lin_relu_kernel<<<GG, 64, 0, stream>>>(z1, l2W, l2b, z2, DENSE);
    lin3_softmax_kernel<<<1, GG, 0, stream>>>(z2, l3W, l3b, outp);
}

// Round 12
// 590.443 us; speedup vs baseline: 1.0430x; 1.0430x over previous
//
#include <hip/hip_runtime.h>

#define N_NODES 50000
#define E_EDGES 800000
#define E2 (E_EDGES + N_NODES)
#define HC 256
#define NHEAD 4
#define GG 128
#define DENSE 64
#define NCLS 2
#define BN_EPS 1e-5f
#define NEG_SLOPE 0.2f
#define NEG_BIG -1e30f

typedef __attribute__((ext_vector_type(8))) short bf16x8;
typedef __attribute__((ext_vector_type(4))) float f32x4;

__device__ __forceinline__ unsigned short f2bf(float f) {
    unsigned int u = __float_as_uint(f);
    u = (u + 0x7FFFu + ((u >> 16) & 1u)) >> 16;
    return (unsigned short)u;
}
__device__ __forceinline__ float bf2f(unsigned short h) {
    return __uint_as_float(((unsigned int)h) << 16);
}
__device__ __forceinline__ float lrelu(float e) {
    return (e >= 0.f) ? e : NEG_SLOPE * e;
}
// accumulate 8 bf16 (packed in uint4) * w into acc[8]; lo=shift, hi=mask (no cvt)
__device__ __forceinline__ void accum8(float acc[8], uint4 v, float w) {
    acc[0] = fmaf(w, __uint_as_float(v.x << 16), acc[0]);
    acc[1] = fmaf(w, __uint_as_float(v.x & 0xffff0000u), acc[1]);
    acc[2] = fmaf(w, __uint_as_float(v.y << 16), acc[2]);
    acc[3] = fmaf(w, __uint_as_float(v.y & 0xffff0000u), acc[3]);
    acc[4] = fmaf(w, __uint_as_float(v.z << 16), acc[4]);
    acc[5] = fmaf(w, __uint_as_float(v.z & 0xffff0000u), acc[5]);
    acc[6] = fmaf(w, __uint_as_float(v.w << 16), acc[6]);
    acc[7] = fmaf(w, __uint_as_float(v.w & 0xffff0000u), acc[7]);
}

// ---------------- pack 3x W [256,256] fp32 into MFMA b-fragment order, bf16 ----------------
__global__ __launch_bounds__(64) void pack_b_kernel(const float* __restrict__ W1,
                                                    const float* __restrict__ Wl,
                                                    unsigned short* __restrict__ Bpk) {
    int l = threadIdx.x;
    int mat = blockIdx.x >> 7;          // 0..2
    int g = blockIdx.x & 127;           // ks*16+ct
    const float* W = (mat == 0) ? W1 : Wl + (size_t)(mat - 1) * HC * HC;
    int ks = g >> 4, ct = g & 15;
    int col = ct * 16 + (l & 15);
    int k0 = ks * 32 + (l >> 4) * 8;
    unsigned short v[8];
#pragma unroll
    for (int j = 0; j < 8; ++j) v[j] = f2bf(W[(size_t)(k0 + j) * HC + col]);
    ushort4* q = reinterpret_cast<ushort4*>(Bpk + ((size_t)mat * 128 * 512) + ((size_t)g * 64 + l) * 8);
    q[0] = make_ushort4(v[0], v[1], v[2], v[3]);
    q[1] = make_ushort4(v[4], v[5], v[6], v[7]);
}

// ---------------- MFMA GEMM + optional fp32-A staging / BN-affine staging ----------------
__global__ __launch_bounds__(256) void gemm_mfma_kernel(const unsigned short* __restrict__ A,
                                                        const float* __restrict__ A32,
                                                        const unsigned short* __restrict__ Bpk,
                                                        const float* __restrict__ prm,
                                                        unsigned short* __restrict__ C, int M) {
    __shared__ unsigned short As[64 * 256];  // 32 KB, XOR-swizzled rows
    int tid = threadIdx.x;
    int lane = tid & 63, wid = tid >> 6;
    int row0 = blockIdx.x * 64;
#pragma unroll
    for (int i = 0; i < 8; ++i) {
        int idx = tid + i * 256;
        int row = idx >> 5, c16 = idx & 31;
        int grow = row0 + row;
        uint4 v = make_uint4(0u, 0u, 0u, 0u);
        if (A32) {
            if (grow < M) {
                const float4* p = reinterpret_cast<const float4*>(A32 + (size_t)grow * HC + c16 * 8);
                float4 a = p[0], b = p[1];
                v.x = (unsigned int)f2bf(a.x) | ((unsigned int)f2bf(a.y) << 16);
                v.y = (unsigned int)f2bf(a.z) | ((unsigned int)f2bf(a.w) << 16);
                v.z = (unsigned int)f2bf(b.x) | ((unsigned int)f2bf(b.y) << 16);
                v.w = (unsigned int)f2bf(b.z) | ((unsigned int)f2bf(b.w) << 16);
            }
        } else {
            if (grow < M) v = *reinterpret_cast<const uint4*>(A + (size_t)grow * HC + c16 * 8);
            if (prm) {
                int ch = c16 * 8;
                const float4 s0 = *reinterpret_cast<const float4*>(prm + ch);
                const float4 s1 = *reinterpret_cast<const float4*>(prm + ch + 4);
                const float4 t0 = *reinterpret_cast<const float4*>(prm + HC + ch);
                const float4 t1 = *reinterpret_cast<const float4*>(prm + HC + ch + 4);
                float f0 = fmaxf(fmaf(__uint_as_float(v.x << 16),          s0.x, t0.x), 0.f);
                float f1 = fmaxf(fmaf(__uint_as_float(v.x & 0xffff0000u),  s0.y, t0.y), 0.f);
                float f2 = fmaxf(fmaf(__uint_as_float(v.y << 16),          s0.z, t0.z), 0.f);
                float f3 = fmaxf(fmaf(__uint_as_float(v.y & 0xffff0000u),  s0.w, t0.w), 0.f);
                float f4 = fmaxf(fmaf(__uint_as_float(v.z << 16),          s1.x, t1.x), 0.f);
                float f5 = fmaxf(fmaf(__uint_as_float(v.z & 0xffff0000u),  s1.y, t1.y), 0.f);
                float f6 = fmaxf(fmaf(__uint_as_float(v.w << 16),          s1.z, t1.z), 0.f);
                float f7 = fmaxf(fmaf(__uint_as_float(v.w & 0xffff0000u),  s1.w, t1.w), 0.f);
                v.x = (unsigned int)f2bf(f0) | ((unsigned int)f2bf(f1) << 16);
                v.y = (unsigned int)f2bf(f2) | ((unsigned int)f2bf(f3) << 16);
                v.z = (unsigned int)f2bf(f4) | ((unsigned int)f2bf(f5) << 16);
                v.w = (unsigned int)f2bf(f6) | ((unsigned int)f2bf(f7) << 16);
            }
        }
        int byteoff = row * 512 + c16 * 16;
        byteoff ^= (row & 7) << 4;
        *reinterpret_cast<uint4*>((char*)As + byteoff) = v;
    }
    __syncthreads();

    f32x4 acc[16];
#pragma unroll
    for (int ct = 0; ct < 16; ++ct) acc[ct] = (f32x4){0.f, 0.f, 0.f, 0.f};

    int mrow = wid * 16 + (lane & 15);
#pragma unroll
    for (int ks = 0; ks < 8; ++ks) {
        int abyte = mrow * 512 + ks * 64 + (lane >> 4) * 16;
        abyte ^= (mrow & 7) << 4;
        bf16x8 a = *reinterpret_cast<const bf16x8*>((char*)As + abyte);
        const unsigned short* bp = Bpk + ((size_t)(ks * 16) * 512 + lane * 8);
#pragma unroll
        for (int ct = 0; ct < 16; ++ct) {
            bf16x8 b = *reinterpret_cast<const bf16x8*>(bp + (size_t)ct * 512);
            acc[ct] = __builtin_amdgcn_mfma_f32_16x16x32_bf16(a, b, acc[ct], 0, 0, 0);
        }
    }
    int crow0 = row0 + wid * 16 + (lane >> 4) * 4;
    int ccol = lane & 15;
#pragma unroll
    for (int ct = 0; ct < 16; ++ct) {
#pragma unroll
        for (int r = 0; r < 4; ++r) {
            int grow = crow0 + r;
            if (grow < M) C[(size_t)grow * HC + ct * 16 + ccol] = f2bf(acc[ct][r]);
        }
    }
}

// ---------------- attention coefficients es/ed per node (bf16 h) ----------------
__global__ __launch_bounds__(256) void esed_kernel(const unsigned short* __restrict__ h,
                                                   const float* __restrict__ avs,
                                                   const float* __restrict__ avd,
                                                   float* __restrict__ es, float* __restrict__ ed) {
    int tid = threadIdx.x;
    int lane = tid & 63, wid = tid >> 6;
    int node = blockIdx.x * 4 + wid;
    if (node >= N_NODES) return;
    int ch0 = lane * 4;
    ushort4 hv = *reinterpret_cast<const ushort4*>(h + (size_t)node * HC + ch0);
    float4 sa = *reinterpret_cast<const float4*>(avs + ch0);
    float4 da = *reinterpret_cast<const float4*>(avd + ch0);
    float h0 = bf2f(hv.x), h1 = bf2f(hv.y), h2 = bf2f(hv.z), h3 = bf2f(hv.w);
    float vs = h0 * sa.x + h1 * sa.y + h2 * sa.z + h3 * sa.w;
    float vd = h0 * da.x + h1 * da.y + h2 * da.z + h3 * da.w;
#pragma unroll
    for (int m = 1; m < 16; m <<= 1) {
        vs += __shfl_xor(vs, m, 64);
        vd += __shfl_xor(vd, m, 64);
    }
    if ((lane & 15) == 0) {
        es[node * NHEAD + (lane >> 4)] = vs;
        ed[node * NHEAD + (lane >> 4)] = vd;
    }
}

// ---------------- CSR build ----------------
__global__ void init_deg_kernel(int* __restrict__ deg) {
    int i = blockIdx.x * blockDim.x + threadIdx.x;
    if (i < N_NODES) deg[i] = 1;  // self loop
}
__global__ void count_edges_kernel(const int* __restrict__ dst, int* __restrict__ deg) {
    int i = blockIdx.x * blockDim.x + threadIdx.x;
    if (i < E_EDGES) atomicAdd(&deg[dst[i]], 1);
}
__global__ __launch_bounds__(1024) void scan1_kernel(const int* __restrict__ deg,
                                                     int* __restrict__ rs, int* __restrict__ bsum) {
    __shared__ int wsum[16];
    int t = threadIdx.x, lane = t & 63, wid = t >> 6;
    int i = blockIdx.x * 1024 + t;
    int v = (i < N_NODES) ? deg[i] : 0;
    int x = v;
#pragma unroll
    for (int off = 1; off < 64; off <<= 1) {
        int y = __shfl_up(x, off, 64);
        if (lane >= off) x += y;
    }
    if (lane == 63) wsum[wid] = x;
    __syncthreads();
    if (wid == 0) {
        int s = (lane < 16) ? wsum[lane] : 0;
#pragma unroll
        for (int off = 1; off < 16; off <<= 1) {
            int y = __shfl_up(s, off, 64);
            if (lane >= off) s += y;
        }
        if (lane < 16) wsum[lane] = s;
    }
    __syncthreads();
    int woff = wid ? wsum[wid - 1] : 0;
    if (i <= N_NODES) rs[i] = woff + x - v;
    if (t == 1023) bsum[blockIdx.x] = wsum[15];
}
__global__ void scan2_kernel(int* __restrict__ bsum, int nb) {
    int l = threadIdx.x;
    int v = (l < nb) ? bsum[l] : 0;
    int x = v;
#pragma unroll
    for (int off = 1; off < 64; off <<= 1) {
        int y = __shfl_up(x, off, 64);
        if (l >= off) x += y;
    }
    if (l < nb) bsum[l] = x - v;
}
// scan3 + self-loop scatter fused: csr[v] = i (self loop first), cursor = v+1
__global__ void scan3_kernel(int* __restrict__ rs, const int* __restrict__ bsum,
                             int* __restrict__ cursor, int* __restrict__ csr) {
    int i = blockIdx.x * blockDim.x + threadIdx.x;
    if (i <= N_NODES) {
        int v = rs[i] + bsum[i >> 10];
        rs[i] = v;
        if (i < N_NODES) {
            csr[v] = i;
            cursor[i] = v + 1;
        }
    }
}
__global__ void scatter_edges_kernel(const int* __restrict__ src, const int* __restrict__ dst,
                                     int* __restrict__ cursor, int* __restrict__ csr) {
    int i = blockIdx.x * blockDim.x + threadIdx.x;
    if (i < E_EDGES) {
        int pos = atomicAdd(&cursor[dst[i]], 1);
        csr[pos] = src[i];
    }
}

// ---------------- softmax prep: (m,s) pass stashes e; rescale pass is streaming ----------------
__global__ __launch_bounds__(256) void smprep_kernel(const float* __restrict__ es,
                                                     const float* __restrict__ ed,
                                                     const int* __restrict__ rs,
                                                     const int* __restrict__ csr,
                                                     float* __restrict__ alpha) {
    int tid = threadIdx.x;
    int lane = tid & 63, wid = tid >> 6;
    int node = blockIdx.x * 4 + wid;
    if (node >= N_NODES) return;
    int head = lane >> 4, slot = lane & 15;
    float edn = ed[node * NHEAD + head];
    int beg = rs[node], end = rs[node + 1];
    // finite sentinel: -inf would produce NaN on empty-slot merges (deg<16 common)
    float m = NEG_BIG, s = 0.f;
    for (int i = beg + slot; i < end; i += 16) {
        float e = lrelu(es[csr[i] * NHEAD + head] + edn);
        alpha[(size_t)i * NHEAD + head] = e;   // stash for pass 2 (coalesced)
        float mn = fmaxf(m, e);
        s = s * __expf(m - mn) + __expf(e - mn);
        m = mn;
    }
#pragma unroll
    for (int off = 1; off < 16; off <<= 1) {  // merge within head group (low 4 bits)
        float mo = __shfl_xor(m, off, 64);
        float so = __shfl_xor(s, off, 64);
        float mn = fmaxf(m, mo);
        s = s * __expf(m - mn) + so * __expf(mo - mn);
        m = mn;
    }
    float inv = 1.f / (s + 1e-16f);
    for (int i = beg + slot; i < end; i += 16) {
        float e = alpha[(size_t)i * NHEAD + head];
        alpha[(size_t)i * NHEAD + head] = __expf(e - m) * inv;
    }
}

// ---------------- GAT aggregation: 2 nodes/wave, 16B/lane, unroll 4 ----------------
__global__ __launch_bounds__(256) void gat_agg_kernel(const unsigned short* __restrict__ hlin,
                                                      const float* __restrict__ alpha,
                                                      const int* __restrict__ rs,
                                                      const int* __restrict__ csr,
                                                      const float* __restrict__ bias,
                                                      unsigned short* __restrict__ out, int do_relu) {
    int tid = threadIdx.x;
    int lane = tid & 63, wid = tid >> 6;
    int node = blockIdx.x * 8 + wid * 2 + (lane >> 5);
    int hl = lane & 31;
    int ch0 = hl * 8;          // 8 channels per lane (16B)
    int head = hl >> 3;
    bool valid = node < N_NODES;
    int beg = valid ? rs[node] : 0;
    int end = valid ? rs[node + 1] : 0;
    float acc[8] = {};
    int idx = beg;
    for (; idx + 4 <= end; idx += 4) {
        int s0 = csr[idx], s1 = csr[idx + 1], s2 = csr[idx + 2], s3 = csr[idx + 3];
        float p0 = alpha[(size_t)idx * NHEAD + head];
        float p1 = alpha[(size_t)(idx + 1) * NHEAD + head];
        float p2 = alpha[(size_t)(idx + 2) * NHEAD + head];
        float p3 = alpha[(size_t)(idx + 3) * NHEAD + head];
        uint4 v0 = *reinterpret_cast<const uint4*>(hlin + (size_t)s0 * HC + ch0);
        uint4 v1 = *reinterpret_cast<const uint4*>(hlin + (size_t)s1 * HC + ch0);
        uint4 v2 = *reinterpret_cast<const uint4*>(hlin + (size_t)s2 * HC + ch0);
        uint4 v3 = *reinterpret_cast<const uint4*>(hlin + (size_t)s3 * HC + ch0);
        accum8(acc, v0, p0);
        accum8(acc, v1, p1);
        accum8(acc, v2, p2);
        accum8(acc, v3, p3);
    }
    for (; idx < end; ++idx) {
        int s0 = csr[idx];
        float p0 = alpha[(size_t)idx * NHEAD + head];
        uint4 v0 = *reinterpret_cast<const uint4*>(hlin + (size_t)s0 * HC + ch0);
        accum8(acc, v0, p0);
    }
    if (!valid) return;
    const float4 bva = *reinterpret_cast<const float4*>(bias + ch0);
    const float4 bvb = *reinterpret_cast<const float4*>(bias + ch0 + 4);
    float o[8];
    o[0] = acc[0] + bva.x; o[1] = acc[1] + bva.y; o[2] = acc[2] + bva.z; o[3] = acc[3] + bva.w;
    o[4] = acc[4] + bvb.x; o[5] = acc[5] + bvb.y; o[6] = acc[6] + bvb.z; o[7] = acc[7] + bvb.w;
    if (do_relu) {
#pragma unroll
        for (int j = 0; j < 8; ++j) o[j] = fmaxf(o[j], 0.f);
    }
    uint4 w;
    w.x = (unsigned int)f2bf(o[0]) | ((unsigned int)f2bf(o[1]) << 16);
    w.y = (unsigned int)f2bf(o[2]) | ((unsigned int)f2bf(o[3]) << 16);
    w.z = (unsigned int)f2bf(o[4]) | ((unsigned int)f2bf(o[5]) << 16);
    w.w = (unsigned int)f2bf(o[6]) | ((unsigned int)f2bf(o[7]) << 16);
    *reinterpret_cast<uint4*>(out + (size_t)node * HC + ch0) = w;
}

// ---------------- BatchNorm stats: 8 row-threads x 32 ch-threads, 16B loads ----------------
#define BN_RPB 49
__global__ __launch_bounds__(256) void bn_stats_kernel(const unsigned short* __restrict__ x,
                                                       float* __restrict__ sums) {
    __shared__ float lds[8][512];
    int tid = threadIdx.x;
    int c = tid & 31;   // channels c*8 .. c*8+7
    int rt = tid >> 5;  // 0..7
    int r0 = blockIdx.x * BN_RPB;
    int r1 = min(N_NODES, r0 + BN_RPB);
    int ch = c * 8;
    float s[8] = {}, s2[8] = {};
    for (int r = r0 + rt; r < r1; r += 8) {
        const ushort4* p = reinterpret_cast<const ushort4*>(x + (size_t)r * HC + ch);
        ushort4 va = p[0], vb = p[1];
        unsigned short in[8] = {va.x, va.y, va.z, va.w, vb.x, vb.y, vb.z, vb.w};
#pragma unroll
        for (int j = 0; j < 8; ++j) {
            float v = bf2f(in[j]);
            s[j] += v; s2[j] += v * v;
        }
    }
#pragma unroll
    for (int j = 0; j < 8; ++j) {
        lds[rt][ch + j] = s[j];
        lds[rt][256 + ch + j] = s2[j];
    }
    __syncthreads();
#pragma unroll
    for (int e = tid; e < 512; e += 256) {
        float v = 0.f;
#pragma unroll
        for (int r = 0; r < 8; ++r) v += lds[r][e];
        atomicAdd(&sums[e], v);
    }
}
__global__ void bn_finalize_kernel(const float* __restrict__ sums, const float* __restrict__ g,
                                   const float* __restrict__ b, float* __restrict__ prm) {
    int t = threadIdx.x;  // 256
    float mean = sums[t] / (float)N_NODES;
    float var = sums[HC + t] / (float)N_NODES - mean * mean;
    var = fmaxf(var, 0.f);
    float scale = g[t] * rsqrtf(var + BN_EPS);
    prm[t] = scale;
    prm[HC + t] = b[t] - mean * scale;
}

// ---------------- pooling (fused BN affine + ReLU on h2) ----------------
#define POOL_RPB 32
__global__ __launch_bounds__(256) void pool_kernel(const unsigned short* __restrict__ h,
                                                   const float* __restrict__ prm,
                                                   const int* __restrict__ batch,
                                                   float* __restrict__ psum) {
    int tid = threadIdx.x;
    int ct = tid & 63;   // channels ct*4 .. ct*4+3
    int rt = tid >> 6;   // 0..3
    int r0 = blockIdx.x * POOL_RPB;
    int r1 = min(N_NODES, r0 + POOL_RPB);
    int ch = ct * 4;
    const float4 sc = *reinterpret_cast<const float4*>(prm + ch);
    const float4 sh = *reinterpret_cast<const float4*>(prm + HC + ch);
    float a0 = 0.f, a1 = 0.f, a2 = 0.f, a3 = 0.f;
    int gcur = -1;
    for (int r = r0 + rt; r < r1; r += 4) {
        int g = batch[r];
        if (g != gcur) {
            if (gcur >= 0) {
                atomicAdd(&psum[gcur * HC + ch + 0], a0);
                atomicAdd(&psum[gcur * HC + ch + 1], a1);
                atomicAdd(&psum[gcur * HC + ch + 2], a2);
                atomicAdd(&psum[gcur * HC + ch + 3], a3);
            }
            a0 = a1 = a2 = a3 = 0.f; gcur = g;
        }
        ushort4 hv = *reinterpret_cast<const ushort4*>(h + (size_t)r * HC + ch);
        a0 += fmaxf(fmaf(bf2f(hv.x), sc.x, sh.x), 0.f);
        a1 += fmaxf(fmaf(bf2f(hv.y), sc.y, sh.y), 0.f);
        a2 += fmaxf(fmaf(bf2f(hv.z), sc.z, sh.z), 0.f);
        a3 += fmaxf(fmaf(bf2f(hv.w), sc.w, sh.w), 0.f);
    }
    if (gcur >= 0) {
        atomicAdd(&psum[gcur * HC + ch + 0], a0);
        atomicAdd(&psum[gcur * HC + ch + 1], a1);
        atomicAdd(&psum[gcur * HC + ch + 2], a2);
        atomicAdd(&psum[gcur * HC + ch + 3], a3);
    }
}
// pool_fin with inline binary-search counts (batch sorted)
__global__ void pool_fin_kernel(const float* __restrict__ psum, const int* __restrict__ batch,
                                float* __restrict__ pooled) {
    int g = blockIdx.x, t = threadIdx.x;
    int lo = 0, hi = N_NODES;
    while (lo < hi) { int mid = (lo + hi) >> 1; if (batch[mid] <= g) lo = mid + 1; else hi = mid; }
    int lo2 = 0, hi2 = N_NODES;
    while (lo2 < hi2) { int mid = (lo2 + hi2) >> 1; if (batch[mid] <= g - 1) lo2 = mid + 1; else hi2 = mid; }
    float cf = fmaxf((float)(lo - lo2), 1.f);
    pooled[g * HC + t] = psum[g * HC + t] / cf;
}

// ---------------- head ----------------
__global__ __launch_bounds__(256) void bn_head_kernel(const float* __restrict__ pooled,
                                                      const float* __restrict__ g,
                                                      const float* __restrict__ b,
                                                      float* __restrict__ z) {
    int t = threadIdx.x;  // channel
    float s = 0.f, s2 = 0.f;
    for (int r = 0; r < GG; ++r) {
        float v = pooled[r * HC + t];
        s += v; s2 += v * v;
    }
    float mean = s / (float)GG;
    float var = fmaxf(s2 / (float)GG - mean * mean, 0.f);
    float scale = g[t] * rsqrtf(var + BN_EPS);
    float shift = b[t] - mean * scale;
    for (int r = 0; r < GG; ++r)
        z[r * HC + t] = pooled[r * HC + t] * scale + shift;
}
__global__ __launch_bounds__(64) void lin_relu_kernel(const float* __restrict__ X,
                                                      const float* __restrict__ W,
                                                      const float* __restrict__ b,
                                                      float* __restrict__ Y, int K) {
    __shared__ float xr[256];
    int r = blockIdx.x, t = threadIdx.x;
    for (int k = t; k < K; k += 64) xr[k] = X[r * K + k];
    __syncthreads();
    float a = b[t];
    for (int k = 0; k < K; ++k) a += xr[k] * W[k * DENSE + t];
    Y[r * DENSE + t] = fmaxf(a, 0.f);
}
__global__ __launch_bounds__(128) void lin3_softmax_kernel(const float* __restrict__ X,
                                                           const float* __restrict__ W,
                                                           const float* __restrict__ b,
                                                           float* __restrict__ out) {
    int r = threadIdx.x;  // 128 rows
    const float* xr = X + r * DENSE;
    float o0 = b[0], o1 = b[1];
    for (int k = 0; k < DENSE; ++k) {
        o0 += xr[k] * W[k * NCLS + 0];
        o1 += xr[k] * W[k * NCLS + 1];
    }
    o0 = fmaxf(o0, 0.f); o1 = fmaxf(o1, 0.f);
    float mx = fmaxf(o0, o1);
    float e0 = __expf(o0 - mx), e1 = __expf(o1 - mx);
    float inv = 1.f / (e0 + e1);
    out[r * NCLS + 0] = e0 * inv;
    out[r * NCLS + 1] = e1 * inv;
}

extern "C" void kernel_launch(void* const* d_in, const int* in_sizes, int n_in,
                              void* d_out, int out_size, void* d_ws, size_t ws_size,
                              hipStream_t stream) {
    const float* x     = (const float*)d_in[0];
    const int*   ei    = (const int*)d_in[1];
    const int*   srcp  = ei;
    const int*   dstp  = ei + E_EDGES;
    const int*   batch = (const int*)d_in[2];
    const float* W1    = (const float*)d_in[3];
    const float* as1   = (const float*)d_in[4];
    const float* ad1   = (const float*)d_in[5];
    const float* b1    = (const float*)d_in[6];
    const float* Wl    = (const float*)d_in[7];
    const float* asl   = (const float*)d_in[8];
    const float* adl   = (const float*)d_in[9];
    const float* bl    = (const float*)d_in[10];
    const float* bng   = (const float*)d_in[11];
    const float* bnb   = (const float*)d_in[12];
    const float* bn1g  = (const float*)d_in[13];
    const float* bn1b  = (const float*)d_in[14];
    const float* l1W   = (const float*)d_in[15];
    const float* l1b   = (const float*)d_in[16];
    const float* l2W   = (const float*)d_in[17];
    const float* l2b   = (const float*)d_in[18];
    const float* l3W   = (const float*)d_in[19];
    const float* l3b   = (const float*)d_in[20];

    float* outp   = (float*)d_out;            // [128,2]
    float* pooled = outp + GG * NCLS;         // [128,256]

    char* w = (char*)d_ws;
    auto alloc = [&](size_t bytes) -> void* {
        void* p = (void*)w;
        w += (bytes + 255) & ~(size_t)255;
        return p;
    };
    unsigned short* h0  = (unsigned short*)alloc(sizeof(short) * (size_t)N_NODES * HC);
    unsigned short* h1  = (unsigned short*)alloc(sizeof(short) * (size_t)N_NODES * HC);
    unsigned short* h2  = (unsigned short*)alloc(sizeof(short) * (size_t)N_NODES * HC);
    unsigned short* Bpk = (unsigned short*)alloc(sizeof(short) * 3 * 128 * 64 * 8);
    float* es     = (float*)alloc(sizeof(float) * (size_t)N_NODES * NHEAD);
    float* ed     = (float*)alloc(sizeof(float) * (size_t)N_NODES * NHEAD);
    float* alpha  = (float*)alloc(sizeof(float) * (size_t)E2 * NHEAD);
    int*   rs     = (int*)alloc(sizeof(int) * (N_NODES + 1));
    int*   deg    = (int*)alloc(sizeof(int) * N_NODES);  // reused as cursor
    int*   csr    = (int*)alloc(sizeof(int) * E2);
    int*   bsum   = (int*)alloc(sizeof(int) * 64);
    float* bnsums = (float*)alloc(sizeof(float) * 2 * HC);
    float* bnprm  = (float*)alloc(sizeof(float) * 2 * HC);
    float* psum   = (float*)alloc(sizeof(float) * GG * HC);
    float* z0     = (float*)alloc(sizeof(float) * GG * HC);
    float* z1     = (float*)alloc(sizeof(float) * GG * DENSE);
    float* z2     = (float*)alloc(sizeof(float) * GG * DENSE);

    const int nblk_nodes = (N_NODES + 255) / 256;
    const int nblk_edges = (E_EDGES + 255) / 256;
    const int nblk_wave4 = (N_NODES + 3) / 4;
    const int nblk_wave8 = (N_NODES + 7) / 8;            // 6250 (2 nodes/wave)
    const int nscan = (N_NODES + 1023) / 1024;           // 49
    const int nblk_bn   = (N_NODES + BN_RPB - 1) / BN_RPB;     // 1021
    const int nblk_pool = (N_NODES + POOL_RPB - 1) / POOL_RPB; // 1563

    // ---- pack weights (3 matrices, one dispatch) ----
    pack_b_kernel<<<384, 64, 0, stream>>>(W1, Wl, Bpk);

    // ---- CSR build ----
    init_deg_kernel<<<nblk_nodes, 256, 0, stream>>>(deg);
    count_edges_kernel<<<nblk_edges, 256, 0, stream>>>(dstp, deg);
    scan1_kernel<<<nscan, 1024, 0, stream>>>(deg, rs, bsum);
    scan2_kernel<<<1, 64, 0, stream>>>(bsum, nscan);
    scan3_kernel<<<(N_NODES + 256) / 256, 256, 0, stream>>>(rs, bsum, deg, csr);
    scatter_edges_kernel<<<nblk_edges, 256, 0, stream>>>(srcp, dstp, deg, csr);

    const int ggrid = (N_NODES + 63) / 64;

    // ---- layer 1: gemm reads fp32 x directly; h0 = relu(gat(x)) ----
    gemm_mfma_kernel<<<ggrid, 256, 0, stream>>>(nullptr, x, Bpk, nullptr, h1, N_NODES);
    esed_kernel<<<nblk_wave4, 256, 0, stream>>>(h1, as1, ad1, es, ed);
    smprep_kernel<<<nblk_wave4, 256, 0, stream>>>(es, ed, rs, csr, alpha);
    gat_agg_kernel<<<nblk_wave8, 256, 0, stream>>>(h1, alpha, rs, csr, b1, h0, 1);

    // ---- inner layer 0 ----
    gemm_mfma_kernel<<<ggrid, 256, 0, stream>>>(h0, nullptr, Bpk + 128 * 512, nullptr, h1, N_NODES);
    esed_kernel<<<nblk_wave4, 256, 0, stream>>>(h1, asl, adl, es, ed);
    smprep_kernel<<<nblk_wave4, 256, 0, stream>>>(es, ed, rs, csr, alpha);
    gat_agg_kernel<<<nblk_wave8, 256, 0, stream>>>(h1, alpha, rs, csr, bl, h2, 0);
    hipMemsetAsync(bnsums, 0, sizeof(float) * 2 * HC, stream);
    bn_stats_kernel<<<nblk_bn, 256, 0, stream>>>(h2, bnsums);
    bn_finalize_kernel<<<1, 256, 0, stream>>>(bnsums, bng, bnb, bnprm);

    // ---- inner layer 1: gemm reads h2 with fused BN0 affine+relu ----
    gemm_mfma_kernel<<<ggrid, 256, 0, stream>>>(h2, nullptr, Bpk + 2 * 128 * 512, bnprm, h1, N_NODES);
    esed_kernel<<<nblk_wave4, 256, 0, stream>>>(h1, asl + HC, adl + HC, es, ed);
    smprep_kernel<<<nblk_wave4, 256, 0, stream>>>(es, ed, rs, csr, alpha);
    gat_agg_kernel<<<nblk_wave8, 256, 0, stream>>>(h1, alpha, rs, csr, bl + HC, h2, 0);
    hipMemsetAsync(bnsums, 0, sizeof(float) * 2 * HC, stream);
    bn_stats_kernel<<<nblk_bn, 256, 0, stream>>>(h2, bnsums);
    bn_finalize_kernel<<<1, 256, 0, stream>>>(bnsums, bng + HC, bnb + HC, bnprm);

    // ---- pooling (fused BN1 affine+relu) ----
    hipMemsetAsync(psum, 0, sizeof(float) * GG * HC, stream);
    pool_kernel<<<nblk_pool, 256, 0, stream>>>(h2, bnprm, batch, psum);
    pool_fin_kernel<<<GG, HC, 0, stream>>>(psum, batch, pooled);

    // ---- head ----
    bn_head_kernel<<<1, HC, 0, stream>>>(pooled, bn1g, bn1b, z0);
    lin_relu_kernel<<<GG, 64, 0, stream>>>(z0, l1W, l1b, z1, HC);
    lin_relu_kernel<<<GG, 64, 0, stream>>>(z1, l2W, l2b, z2, DENSE);
    lin3_softmax_kernel<<<1, GG, 0, stream>>>(z2, l3W, l3b, outp);
}

// Round 13
// 553.286 us; speedup vs baseline: 1.1130x; 1.0672x over previous
//
#include <hip/hip_runtime.h>

#define N_NODES 50000
#define E_EDGES 800000
#define E2 (E_EDGES + N_NODES)
#define HC 256
#define NHEAD 4
#define GG 128
#define DENSE 64
#define NCLS 2
#define BN_EPS 1e-5f
#define NEG_SLOPE 0.2f
#define NEG_BIG -1e30f

typedef __attribute__((ext_vector_type(8))) short bf16x8;
typedef __attribute__((ext_vector_type(4))) float f32x4;

__device__ __forceinline__ unsigned short f2bf(float f) {
    unsigned int u = __float_as_uint(f);
    u = (u + 0x7FFFu + ((u >> 16) & 1u)) >> 16;
    return (unsigned short)u;
}
__device__ __forceinline__ float bf2f(unsigned short h) {
    return __uint_as_float(((unsigned int)h) << 16);
}
__device__ __forceinline__ float lrelu(float e) {
    return (e >= 0.f) ? e : NEG_SLOPE * e;
}
// accumulate 8 bf16 (packed in uint4) * w into acc[8]; lo=shift, hi=mask (no cvt)
__device__ __forceinline__ void accum8(float acc[8], uint4 v, float w) {
    acc[0] = fmaf(w, __uint_as_float(v.x << 16), acc[0]);
    acc[1] = fmaf(w, __uint_as_float(v.x & 0xffff0000u), acc[1]);
    acc[2] = fmaf(w, __uint_as_float(v.y << 16), acc[2]);
    acc[3] = fmaf(w, __uint_as_float(v.y & 0xffff0000u), acc[3]);
    acc[4] = fmaf(w, __uint_as_float(v.z << 16), acc[4]);
    acc[5] = fmaf(w, __uint_as_float(v.z & 0xffff0000u), acc[5]);
    acc[6] = fmaf(w, __uint_as_float(v.w << 16), acc[6]);
    acc[7] = fmaf(w, __uint_as_float(v.w & 0xffff0000u), acc[7]);
}

// ---------------- pack 3x W [256,256] fp32 into MFMA b-fragment order, bf16 ----------------
__global__ __launch_bounds__(64) void pack_b_kernel(const float* __restrict__ W1,
                                                    const float* __restrict__ Wl,
                                                    unsigned short* __restrict__ Bpk) {
    int l = threadIdx.x;
    int mat = blockIdx.x >> 7;          // 0..2
    int g = blockIdx.x & 127;           // ks*16+ct
    const float* W = (mat == 0) ? W1 : Wl + (size_t)(mat - 1) * HC * HC;
    int ks = g >> 4, ct = g & 15;
    int col = ct * 16 + (l & 15);
    int k0 = ks * 32 + (l >> 4) * 8;
    unsigned short v[8];
#pragma unroll
    for (int j = 0; j < 8; ++j) v[j] = f2bf(W[(size_t)(k0 + j) * HC + col]);
    ushort4* q = reinterpret_cast<ushort4*>(Bpk + ((size_t)mat * 128 * 512) + ((size_t)g * 64 + l) * 8);
    q[0] = make_ushort4(v[0], v[1], v[2], v[3]);
    q[1] = make_ushort4(v[4], v[5], v[6], v[7]);
}

// ---------------- MFMA GEMM: wave = 4 col-tiles x 64 rows (B traffic 4x down) ----------------
__global__ __launch_bounds__(256) void gemm_mfma_kernel(const unsigned short* __restrict__ A,
                                                        const float* __restrict__ A32,
                                                        const unsigned short* __restrict__ Bpk,
                                                        const float* __restrict__ prm,
                                                        unsigned short* __restrict__ C, int M) {
    __shared__ unsigned short As[64 * 256];  // 32 KB, XOR-swizzled rows
    int tid = threadIdx.x;
    int lane = tid & 63, wid = tid >> 6;
    int row0 = blockIdx.x * 64;
#pragma unroll
    for (int i = 0; i < 8; ++i) {
        int idx = tid + i * 256;
        int row = idx >> 5, c16 = idx & 31;
        int grow = row0 + row;
        uint4 v = make_uint4(0u, 0u, 0u, 0u);
        if (A32) {
            if (grow < M) {
                const float4* p = reinterpret_cast<const float4*>(A32 + (size_t)grow * HC + c16 * 8);
                float4 a = p[0], b = p[1];
                v.x = (unsigned int)f2bf(a.x) | ((unsigned int)f2bf(a.y) << 16);
                v.y = (unsigned int)f2bf(a.z) | ((unsigned int)f2bf(a.w) << 16);
                v.z = (unsigned int)f2bf(b.x) | ((unsigned int)f2bf(b.y) << 16);
                v.w = (unsigned int)f2bf(b.z) | ((unsigned int)f2bf(b.w) << 16);
            }
        } else {
            if (grow < M) v = *reinterpret_cast<const uint4*>(A + (size_t)grow * HC + c16 * 8);
            if (prm) {
                int ch = c16 * 8;
                const float4 s0 = *reinterpret_cast<const float4*>(prm + ch);
                const float4 s1 = *reinterpret_cast<const float4*>(prm + ch + 4);
                const float4 t0 = *reinterpret_cast<const float4*>(prm + HC + ch);
                const float4 t1 = *reinterpret_cast<const float4*>(prm + HC + ch + 4);
                float f0 = fmaxf(fmaf(__uint_as_float(v.x << 16),          s0.x, t0.x), 0.f);
                float f1 = fmaxf(fmaf(__uint_as_float(v.x & 0xffff0000u),  s0.y, t0.y), 0.f);
                float f2 = fmaxf(fmaf(__uint_as_float(v.y << 16),          s0.z, t0.z), 0.f);
                float f3 = fmaxf(fmaf(__uint_as_float(v.y & 0xffff0000u),  s0.w, t0.w), 0.f);
                float f4 = fmaxf(fmaf(__uint_as_float(v.z << 16),          s1.x, t1.x), 0.f);
                float f5 = fmaxf(fmaf(__uint_as_float(v.z & 0xffff0000u),  s1.y, t1.y), 0.f);
                float f6 = fmaxf(fmaf(__uint_as_float(v.w << 16),          s1.z, t1.z), 0.f);
                float f7 = fmaxf(fmaf(__uint_as_float(v.w & 0xffff0000u),  s1.w, t1.w), 0.f);
                v.x = (unsigned int)f2bf(f0) | ((unsigned int)f2bf(f1) << 16);
                v.y = (unsigned int)f2bf(f2) | ((unsigned int)f2bf(f3) << 16);
                v.z = (unsigned int)f2bf(f4) | ((unsigned int)f2bf(f5) << 16);
                v.w = (unsigned int)f2bf(f6) | ((unsigned int)f2bf(f7) << 16);
            }
        }
        int byteoff = row * 512 + c16 * 16;
        byteoff ^= (row & 7) << 4;
        *reinterpret_cast<uint4*>((char*)As + byteoff) = v;
    }
    __syncthreads();

    // acc[rt][c]: row-tile rt (16 rows each, 4 tiles = 64 rows), col-tile c of this wave
    f32x4 acc[4][4];
#pragma unroll
    for (int rt = 0; rt < 4; ++rt)
#pragma unroll
        for (int c = 0; c < 4; ++c) acc[rt][c] = (f32x4){0.f, 0.f, 0.f, 0.f};

    int arow = lane & 15;
    int asub = (lane >> 4) * 16;
#pragma unroll
    for (int ks = 0; ks < 8; ++ks) {
        // this wave's 4 B-frags for k-slice ks (col tiles wid*4 .. wid*4+3)
        const unsigned short* bp = Bpk + ((size_t)(ks * 16 + wid * 4) * 512 + lane * 8);
        bf16x8 b0 = *reinterpret_cast<const bf16x8*>(bp);
        bf16x8 b1 = *reinterpret_cast<const bf16x8*>(bp + 512);
        bf16x8 b2 = *reinterpret_cast<const bf16x8*>(bp + 1024);
        bf16x8 b3 = *reinterpret_cast<const bf16x8*>(bp + 1536);
#pragma unroll
        for (int rt = 0; rt < 4; ++rt) {
            int mrow = rt * 16 + arow;
            int abyte = mrow * 512 + ks * 64 + asub;
            abyte ^= (mrow & 7) << 4;
            bf16x8 a = *reinterpret_cast<const bf16x8*>((char*)As + abyte);
            acc[rt][0] = __builtin_amdgcn_mfma_f32_16x16x32_bf16(a, b0, acc[rt][0], 0, 0, 0);
            acc[rt][1] = __builtin_amdgcn_mfma_f32_16x16x32_bf16(a, b1, acc[rt][1], 0, 0, 0);
            acc[rt][2] = __builtin_amdgcn_mfma_f32_16x16x32_bf16(a, b2, acc[rt][2], 0, 0, 0);
            acc[rt][3] = __builtin_amdgcn_mfma_f32_16x16x32_bf16(a, b3, acc[rt][3], 0, 0, 0);
        }
    }
    // C/D layout: col = lane&15, row = (lane>>4)*4 + r
    int ccol = lane & 15;
#pragma unroll
    for (int rt = 0; rt < 4; ++rt) {
        int crow0 = row0 + rt * 16 + (lane >> 4) * 4;
#pragma unroll
        for (int c = 0; c < 4; ++c) {
            int gcol = (wid * 4 + c) * 16 + ccol;
#pragma unroll
            for (int r = 0; r < 4; ++r) {
                int grow = crow0 + r;
                if (grow < M) C[(size_t)grow * HC + gcol] = f2bf(acc[rt][c][r]);
            }
        }
    }
}

// ---------------- attention coefficients es/ed per node (bf16 h) ----------------
__global__ __launch_bounds__(256) void esed_kernel(const unsigned short* __restrict__ h,
                                                   const float* __restrict__ avs,
                                                   const float* __restrict__ avd,
                                                   float* __restrict__ es, float* __restrict__ ed) {
    int tid = threadIdx.x;
    int lane = tid & 63, wid = tid >> 6;
    int node = blockIdx.x * 4 + wid;
    if (node >= N_NODES) return;
    int ch0 = lane * 4;
    ushort4 hv = *reinterpret_cast<const ushort4*>(h + (size_t)node * HC + ch0);
    float4 sa = *reinterpret_cast<const float4*>(avs + ch0);
    float4 da = *reinterpret_cast<const float4*>(avd + ch0);
    float h0 = bf2f(hv.x), h1 = bf2f(hv.y), h2 = bf2f(hv.z), h3 = bf2f(hv.w);
    float vs = h0 * sa.x + h1 * sa.y + h2 * sa.z + h3 * sa.w;
    float vd = h0 * da.x + h1 * da.y + h2 * da.z + h3 * da.w;
#pragma unroll
    for (int m = 1; m < 16; m <<= 1) {
        vs += __shfl_xor(vs, m, 64);
        vd += __shfl_xor(vd, m, 64);
    }
    if ((lane & 15) == 0) {
        es[node * NHEAD + (lane >> 4)] = vs;
        ed[node * NHEAD + (lane >> 4)] = vd;
    }
}

// ---------------- CSR build ----------------
__global__ void init_deg_kernel(int* __restrict__ deg) {
    int i = blockIdx.x * blockDim.x + threadIdx.x;
    if (i < N_NODES) deg[i] = 1;  // self loop
}
__global__ void count_edges_kernel(const int* __restrict__ dst, int* __restrict__ deg) {
    int i = blockIdx.x * blockDim.x + threadIdx.x;
    if (i < E_EDGES) atomicAdd(&deg[dst[i]], 1);
}
__global__ __launch_bounds__(1024) void scan1_kernel(const int* __restrict__ deg,
                                                     int* __restrict__ rs, int* __restrict__ bsum) {
    __shared__ int wsum[16];
    int t = threadIdx.x, lane = t & 63, wid = t >> 6;
    int i = blockIdx.x * 1024 + t;
    int v = (i < N_NODES) ? deg[i] : 0;
    int x = v;
#pragma unroll
    for (int off = 1; off < 64; off <<= 1) {
        int y = __shfl_up(x, off, 64);
        if (lane >= off) x += y;
    }
    if (lane == 63) wsum[wid] = x;
    __syncthreads();
    if (wid == 0) {
        int s = (lane < 16) ? wsum[lane] : 0;
#pragma unroll
        for (int off = 1; off < 16; off <<= 1) {
            int y = __shfl_up(s, off, 64);
            if (lane >= off) s += y;
        }
        if (lane < 16) wsum[lane] = s;
    }
    __syncthreads();
    int woff = wid ? wsum[wid - 1] : 0;
    if (i <= N_NODES) rs[i] = woff + x - v;
    if (t == 1023) bsum[blockIdx.x] = wsum[15];
}
__global__ void scan2_kernel(int* __restrict__ bsum, int nb) {
    int l = threadIdx.x;
    int v = (l < nb) ? bsum[l] : 0;
    int x = v;
#pragma unroll
    for (int off = 1; off < 64; off <<= 1) {
        int y = __shfl_up(x, off, 64);
        if (l >= off) x += y;
    }
    if (l < nb) bsum[l] = x - v;
}
// scan3 + self-loop scatter fused: csr[v] = i (self loop first), cursor = v+1
__global__ void scan3_kernel(int* __restrict__ rs, const int* __restrict__ bsum,
                             int* __restrict__ cursor, int* __restrict__ csr) {
    int i = blockIdx.x * blockDim.x + threadIdx.x;
    if (i <= N_NODES) {
        int v = rs[i] + bsum[i >> 10];
        rs[i] = v;
        if (i < N_NODES) {
            csr[v] = i;
            cursor[i] = v + 1;
        }
    }
}
__global__ void scatter_edges_kernel(const int* __restrict__ src, const int* __restrict__ dst,
                                     int* __restrict__ cursor, int* __restrict__ csr) {
    int i = blockIdx.x * blockDim.x + threadIdx.x;
    if (i < E_EDGES) {
        int pos = atomicAdd(&cursor[dst[i]], 1);
        csr[pos] = src[i];
    }
}

// ---------------- softmax prep: (m,s) pass stashes e; rescale pass is streaming ----------------
__global__ __launch_bounds__(256) void smprep_kernel(const float* __restrict__ es,
                                                     const float* __restrict__ ed,
                                                     const int* __restrict__ rs,
                                                     const int* __restrict__ csr,
                                                     float* __restrict__ alpha) {
    int tid = threadIdx.x;
    int lane = tid & 63, wid = tid >> 6;
    int node = blockIdx.x * 4 + wid;
    if (node >= N_NODES) return;
    int head = lane >> 4, slot = lane & 15;
    float edn = ed[node * NHEAD + head];
    int beg = rs[node], end = rs[node + 1];
    // finite sentinel: -inf would produce NaN on empty-slot merges (deg<16 common)
    float m = NEG_BIG, s = 0.f;
    for (int i = beg + slot; i < end; i += 16) {
        float e = lrelu(es[csr[i] * NHEAD + head] + edn);
        alpha[(size_t)i * NHEAD + head] = e;   // stash for pass 2 (coalesced)
        float mn = fmaxf(m, e);
        s = s * __expf(m - mn) + __expf(e - mn);
        m = mn;
    }
#pragma unroll
    for (int off = 1; off < 16; off <<= 1) {  // merge within head group (low 4 bits)
        float mo = __shfl_xor(m, off, 64);
        float so = __shfl_xor(s, off, 64);
        float mn = fmaxf(m, mo);
        s = s * __expf(m - mn) + so * __expf(mo - mn);
        m = mn;
    }
    float inv = 1.f / (s + 1e-16f);
    for (int i = beg + slot; i < end; i += 16) {
        float e = alpha[(size_t)i * NHEAD + head];
        alpha[(size_t)i * NHEAD + head] = __expf(e - m) * inv;
    }
}

// ---------------- GAT aggregation: 2 nodes/wave, 16B/lane, unroll 4 ----------------
__global__ __launch_bounds__(256) void gat_agg_kernel(const unsigned short* __restrict__ hlin,
                                                      const float* __restrict__ alpha,
                                                      const int* __restrict__ rs,
                                                      const int* __restrict__ csr,
                                                      const float* __restrict__ bias,
                                                      unsigned short* __restrict__ out, int do_relu) {
    int tid = threadIdx.x;
    int lane = tid & 63, wid = tid >> 6;
    int node = blockIdx.x * 8 + wid * 2 + (lane >> 5);
    int hl = lane & 31;
    int ch0 = hl * 8;          // 8 channels per lane (16B)
    int head = hl >> 3;
    bool valid = node < N_NODES;
    int beg = valid ? rs[node] : 0;
    int end = valid ? rs[node + 1] : 0;
    float acc[8] = {};
    int idx = beg;
    for (; idx + 4 <= end; idx += 4) {
        int s0 = csr[idx], s1 = csr[idx + 1], s2 = csr[idx + 2], s3 = csr[idx + 3];
        float p0 = alpha[(size_t)idx * NHEAD + head];
        float p1 = alpha[(size_t)(idx + 1) * NHEAD + head];
        float p2 = alpha[(size_t)(idx + 2) * NHEAD + head];
        float p3 = alpha[(size_t)(idx + 3) * NHEAD + head];
        uint4 v0 = *reinterpret_cast<const uint4*>(hlin + (size_t)s0 * HC + ch0);
        uint4 v1 = *reinterpret_cast<const uint4*>(hlin + (size_t)s1 * HC + ch0);
        uint4 v2 = *reinterpret_cast<const uint4*>(hlin + (size_t)s2 * HC + ch0);
        uint4 v3 = *reinterpret_cast<const uint4*>(hlin + (size_t)s3 * HC + ch0);
        accum8(acc, v0, p0);
        accum8(acc, v1, p1);
        accum8(acc, v2, p2);
        accum8(acc, v3, p3);
    }
    for (; idx < end; ++idx) {
        int s0 = csr[idx];
        float p0 = alpha[(size_t)idx * NHEAD + head];
        uint4 v0 = *reinterpret_cast<const uint4*>(hlin + (size_t)s0 * HC + ch0);
        accum8(acc, v0, p0);
    }
    if (!valid) return;
    const float4 bva = *reinterpret_cast<const float4*>(bias + ch0);
    const float4 bvb = *reinterpret_cast<const float4*>(bias + ch0 + 4);
    float o[8];
    o[0] = acc[0] + bva.x; o[1] = acc[1] + bva.y; o[2] = acc[2] + bva.z; o[3] = acc[3] + bva.w;
    o[4] = acc[4] + bvb.x; o[5] = acc[5] + bvb.y; o[6] = acc[6] + bvb.z; o[7] = acc[7] + bvb.w;
    if (do_relu) {
#pragma unroll
        for (int j = 0; j < 8; ++j) o[j] = fmaxf(o[j], 0.f);
    }
    uint4 w;
    w.x = (unsigned int)f2bf(o[0]) | ((unsigned int)f2bf(o[1]) << 16);
    w.y = (unsigned int)f2bf(o[2]) | ((unsigned int)f2bf(o[3]) << 16);
    w.z = (unsigned int)f2bf(o[4]) | ((unsigned int)f2bf(o[5]) << 16);
    w.w = (unsigned int)f2bf(o[6]) | ((unsigned int)f2bf(o[7]) << 16);
    *reinterpret_cast<uint4*>(out + (size_t)node * HC + ch0) = w;
}

// ---------------- BatchNorm stats: 8 row-threads x 32 ch-threads, 16B loads ----------------
#define BN_RPB 49
__global__ __launch_bounds__(256) void bn_stats_kernel(const unsigned short* __restrict__ x,
                                                       float* __restrict__ sums) {
    __shared__ float lds[8][512];
    int tid = threadIdx.x;
    int c = tid & 31;   // channels c*8 .. c*8+7
    int rt = tid >> 5;  // 0..7
    int r0 = blockIdx.x * BN_RPB;
    int r1 = min(N_NODES, r0 + BN_RPB);
    int ch = c * 8;
    float s[8] = {}, s2[8] = {};
    for (int r = r0 + rt; r < r1; r += 8) {
        const ushort4* p = reinterpret_cast<const ushort4*>(x + (size_t)r * HC + ch);
        ushort4 va = p[0], vb = p[1];
        unsigned short in[8] = {va.x, va.y, va.z, va.w, vb.x, vb.y, vb.z, vb.w};
#pragma unroll
        for (int j = 0; j < 8; ++j) {
            float v = bf2f(in[j]);
            s[j] += v; s2[j] += v * v;
        }
    }
#pragma unroll
    for (int j = 0; j < 8; ++j) {
        lds[rt][ch + j] = s[j];
        lds[rt][256 + ch + j] = s2[j];
    }
    __syncthreads();
#pragma unroll
    for (int e = tid; e < 512; e += 256) {
        float v = 0.f;
#pragma unroll
        for (int r = 0; r < 8; ++r) v += lds[r][e];
        atomicAdd(&sums[e], v);
    }
}
__global__ void bn_finalize_kernel(const float* __restrict__ sums, const float* __restrict__ g,
                                   const float* __restrict__ b, float* __restrict__ prm) {
    int t = threadIdx.x;  // 256
    float mean = sums[t] / (float)N_NODES;
    float var = sums[HC + t] / (float)N_NODES - mean * mean;
    var = fmaxf(var, 0.f);
    float scale = g[t] * rsqrtf(var + BN_EPS);
    prm[t] = scale;
    prm[HC + t] = b[t] - mean * scale;
}

// ---------------- pooling (fused BN affine + ReLU on h2) ----------------
#define POOL_RPB 32
__global__ __launch_bounds__(256) void pool_kernel(const unsigned short* __restrict__ h,
                                                   const float* __restrict__ prm,
                                                   const int* __restrict__ batch,
                                                   float* __restrict__ psum) {
    int tid = threadIdx.x;
    int ct = tid & 63;   // channels ct*4 .. ct*4+3
    int rt = tid >> 6;   // 0..3
    int r0 = blockIdx.x * POOL_RPB;
    int r1 = min(N_NODES, r0 + POOL_RPB);
    int ch = ct * 4;
    const float4 sc = *reinterpret_cast<const float4*>(prm + ch);
    const float4 sh = *reinterpret_cast<const float4*>(prm + HC + ch);
    float a0 = 0.f, a1 = 0.f, a2 = 0.f, a3 = 0.f;
    int gcur = -1;
    for (int r = r0 + rt; r < r1; r += 4) {
        int g = batch[r];
        if (g != gcur) {
            if (gcur >= 0) {
                atomicAdd(&psum[gcur * HC + ch + 0], a0);
                atomicAdd(&psum[gcur * HC + ch + 1], a1);
                atomicAdd(&psum[gcur * HC + ch + 2], a2);
                atomicAdd(&psum[gcur * HC + ch + 3], a3);
            }
            a0 = a1 = a2 = a3 = 0.f; gcur = g;
        }
        ushort4 hv = *reinterpret_cast<const ushort4*>(h + (size_t)r * HC + ch);
        a0 += fmaxf(fmaf(bf2f(hv.x), sc.x, sh.x), 0.f);
        a1 += fmaxf(fmaf(bf2f(hv.y), sc.y, sh.y), 0.f);
        a2 += fmaxf(fmaf(bf2f(hv.z), sc.z, sh.z), 0.f);
        a3 += fmaxf(fmaf(bf2f(hv.w), sc.w, sh.w), 0.f);
    }
    if (gcur >= 0) {
        atomicAdd(&psum[gcur * HC + ch + 0], a0);
        atomicAdd(&psum[gcur * HC + ch + 1], a1);
        atomicAdd(&psum[gcur * HC + ch + 2], a2);
        atomicAdd(&psum[gcur * HC + ch + 3], a3);
    }
}
// pool_fin with inline binary-search counts (batch sorted)
__global__ void pool_fin_kernel(const float* __restrict__ psum, const int* __restrict__ batch,
                                float* __restrict__ pooled) {
    int g = blockIdx.x, t = threadIdx.x;
    int lo = 0, hi = N_NODES;
    while (lo < hi) { int mid = (lo + hi) >> 1; if (batch[mid] <= g) lo = mid + 1; else hi = mid; }
    int lo2 = 0, hi2 = N_NODES;
    while (lo2 < hi2) { int mid = (lo2 + hi2) >> 1; if (batch[mid] <= g - 1) lo2 = mid + 1; else hi2 = mid; }
    float cf = fmaxf((float)(lo - lo2), 1.f);
    pooled[g * HC + t] = psum[g * HC + t] / cf;
}

// ---------------- head ----------------
__global__ __launch_bounds__(256) void bn_head_kernel(const float* __restrict__ pooled,
                                                      const float* __restrict__ g,
                                                      const float* __restrict__ b,
                                                      float* __restrict__ z) {
    int t = threadIdx.x;  // channel
    float s = 0.f, s2 = 0.f;
    for (int r = 0; r < GG; ++r) {
        float v = pooled[r * HC + t];
        s += v; s2 += v * v;
    }
    float mean = s / (float)GG;
    float var = fmaxf(s2 / (float)GG - mean * mean, 0.f);
    float scale = g[t] * rsqrtf(var + BN_EPS);
    float shift = b[t] - mean * scale;
    for (int r = 0; r < GG; ++r)
        z[r * HC + t] = pooled[r * HC + t] * scale + shift;
}
__global__ __launch_bounds__(64) void lin_relu_kernel(const float* __restrict__ X,
                                                      const float* __restrict__ W,
                                                      const float* __restrict__ b,
                                                      float* __restrict__ Y, int K) {
    __shared__ float xr[256];
    int r = blockIdx.x, t = threadIdx.x;
    for (int k = t; k < K; k += 64) xr[k] = X[r * K + k];
    __syncthreads();
    float a = b[t];
    for (int k = 0; k < K; ++k) a += xr[k] * W[k * DENSE + t];
    Y[r * DENSE + t] = fmaxf(a, 0.f);
}
__global__ __launch_bounds__(128) void lin3_softmax_kernel(const float* __restrict__ X,
                                                           const float* __restrict__ W,
                                                           const float* __restrict__ b,
                                                           float* __restrict__ out) {
    int r = threadIdx.x;  // 128 rows
    const float* xr = X + r * DENSE;
    float o0 = b[0], o1 = b[1];
    for (int k = 0; k < DENSE; ++k) {
        o0 += xr[k] * W[k * NCLS + 0];
        o1 += xr[k] * W[k * NCLS + 1];
    }
    o0 = fmaxf(o0, 0.f); o1 = fmaxf(o1, 0.f);
    float mx = fmaxf(o0, o1);
    float e0 = __expf(o0 - mx), e1 = __expf(o1 - mx);
    float inv = 1.f / (e0 + e1);
    out[r * NCLS + 0] = e0 * inv;
    out[r * NCLS + 1] = e1 * inv;
}

extern "C" void kernel_launch(void* const* d_in, const int* in_sizes, int n_in,
                              void* d_out, int out_size, void* d_ws, size_t ws_size,
                              hipStream_t stream) {
    const float* x     = (const float*)d_in[0];
    const int*   ei    = (const int*)d_in[1];
    const int*   srcp  = ei;
    const int*   dstp  = ei + E_EDGES;
    const int*   batch = (const int*)d_in[2];
    const float* W1    = (const float*)d_in[3];
    const float* as1   = (const float*)d_in[4];
    const float* ad1   = (const float*)d_in[5];
    const float* b1    = (const float*)d_in[6];
    const float* Wl    = (const float*)d_in[7];
    const float* asl   = (const float*)d_in[8];
    const float* adl   = (const float*)d_in[9];
    const float* bl    = (const float*)d_in[10];
    const float* bng   = (const float*)d_in[11];
    const float* bnb   = (const float*)d_in[12];
    const float* bn1g  = (const float*)d_in[13];
    const float* bn1b  = (const float*)d_in[14];
    const float* l1W   = (const float*)d_in[15];
    const float* l1b   = (const float*)d_in[16];
    const float* l2W   = (const float*)d_in[17];
    const float* l2b   = (const float*)d_in[18];
    const float* l3W   = (const float*)d_in[19];
    const float* l3b   = (const float*)d_in[20];

    float* outp   = (float*)d_out;            // [128,2]
    float* pooled = outp + GG * NCLS;         // [128,256]

    char* w = (char*)d_ws;
    auto alloc = [&](size_t bytes) -> void* {
        void* p = (void*)w;
        w += (bytes + 255) & ~(size_t)255;
        return p;
    };
    unsigned short* h0  = (unsigned short*)alloc(sizeof(short) * (size_t)N_NODES * HC);
    unsigned short* h1  = (unsigned short*)alloc(sizeof(short) * (size_t)N_NODES * HC);
    unsigned short* h2  = (unsigned short*)alloc(sizeof(short) * (size_t)N_NODES * HC);
    unsigned short* Bpk = (unsigned short*)alloc(sizeof(short) * 3 * 128 * 64 * 8);
    float* es     = (float*)alloc(sizeof(float) * (size_t)N_NODES * NHEAD);
    float* ed     = (float*)alloc(sizeof(float) * (size_t)N_NODES * NHEAD);
    float* alpha  = (float*)alloc(sizeof(float) * (size_t)E2 * NHEAD);
    int*   rs     = (int*)alloc(sizeof(int) * (N_NODES + 1));
    int*   deg    = (int*)alloc(sizeof(int) * N_NODES);  // reused as cursor
    int*   csr    = (int*)alloc(sizeof(int) * E2);
    int*   bsum   = (int*)alloc(sizeof(int) * 64);
    float* bnsums = (float*)alloc(sizeof(float) * 2 * HC);
    float* bnprm  = (float*)alloc(sizeof(float) * 2 * HC);
    float* psum   = (float*)alloc(sizeof(float) * GG * HC);
    float* z0     = (float*)alloc(sizeof(float) * GG * HC);
    float* z1     = (float*)alloc(sizeof(float) * GG * DENSE);
    float* z2     = (float*)alloc(sizeof(float) * GG * DENSE);

    const int nblk_nodes = (N_NODES + 255) / 256;
    const int nblk_edges = (E_EDGES + 255) / 256;
    const int nblk_wave4 = (N_NODES + 3) / 4;
    const int nblk_wave8 = (N_NODES + 7) / 8;            // 6250 (2 nodes/wave)
    const int nscan = (N_NODES + 1023) / 1024;           // 49
    const int nblk_bn   = (N_NODES + BN_RPB - 1) / BN_RPB;     // 1021
    const int nblk_pool = (N_NODES + POOL_RPB - 1) / POOL_RPB; // 1563

    // ---- pack weights (3 matrices, one dispatch) ----
    pack_b_kernel<<<384, 64, 0, stream>>>(W1, Wl, Bpk);

    // ---- CSR build ----
    init_deg_kernel<<<nblk_nodes, 256, 0, stream>>>(deg);
    count_edges_kernel<<<nblk_edges, 256, 0, stream>>>(dstp, deg);
    scan1_kernel<<<nscan, 1024, 0, stream>>>(deg, rs, bsum);
    scan2_kernel<<<1, 64, 0, stream>>>(bsum, nscan);
    scan3_kernel<<<(N_NODES + 256) / 256, 256, 0, stream>>>(rs, bsum, deg, csr);
    scatter_edges_kernel<<<nblk_edges, 256, 0, stream>>>(srcp, dstp, deg, csr);

    const int ggrid = (N_NODES + 63) / 64;

    // ---- layer 1: gemm reads fp32 x directly; h0 = relu(gat(x)) ----
    gemm_mfma_kernel<<<ggrid, 256, 0, stream>>>(nullptr, x, Bpk, nullptr, h1, N_NODES);
    esed_kernel<<<nblk_wave4, 256, 0, stream>>>(h1, as1, ad1, es, ed);
    smprep_kernel<<<nblk_wave4, 256, 0, stream>>>(es, ed, rs, csr, alpha);
    gat_agg_kernel<<<nblk_wave8, 256, 0, stream>>>(h1, alpha, rs, csr, b1, h0, 1);

    // ---- inner layer 0 ----
    gemm_mfma_kernel<<<ggrid, 256, 0, stream>>>(h0, nullptr, Bpk + 128 * 512, nullptr, h1, N_NODES);
    esed_kernel<<<nblk_wave4, 256, 0, stream>>>(h1, asl, adl, es, ed);
    smprep_kernel<<<nblk_wave4, 256, 0, stream>>>(es, ed, rs, csr, alpha);
    gat_agg_kernel<<<nblk_wave8, 256, 0, stream>>>(h1, alpha, rs, csr, bl, h2, 0);
    hipMemsetAsync(bnsums, 0, sizeof(float) * 2 * HC, stream);
    bn_stats_kernel<<<nblk_bn, 256, 0, stream>>>(h2, bnsums);
    bn_finalize_kernel<<<1, 256, 0, stream>>>(bnsums, bng, bnb, bnprm);

    // ---- inner layer 1: gemm reads h2 with fused BN0 affine+relu ----
    gemm_mfma_kernel<<<ggrid, 256, 0, stream>>>(h2, nullptr, Bpk + 2 * 128 * 512, bnprm, h1, N_NODES);
    esed_kernel<<<nblk_wave4, 256, 0, stream>>>(h1, asl + HC, adl + HC, es, ed);
    smprep_kernel<<<nblk_wave4, 256, 0, stream>>>(es, ed, rs, csr, alpha);
    gat_agg_kernel<<<nblk_wave8, 256, 0, stream>>>(h1, alpha, rs, csr, bl + HC, h2, 0);
    hipMemsetAsync(bnsums, 0, sizeof(float) * 2 * HC, stream);
    bn_stats_kernel<<<nblk_bn, 256, 0, stream>>>(h2, bnsums);
    bn_finalize_kernel<<<1, 256, 0, stream>>>(bnsums, bng + HC, bnb + HC, bnprm);

    // ---- pooling (fused BN1 affine+relu) ----
    hipMemsetAsync(psum, 0, sizeof(float) * GG * HC, stream);
    pool_kernel<<<nblk_pool, 256, 0, stream>>>(h2, bnprm, batch, psum);
    pool_fin_kernel<<<GG, HC, 0, stream>>>(psum, batch, pooled);

    // ---- head ----
    bn_head_kernel<<<1, HC, 0, stream>>>(pooled, bn1g, bn1b, z0);
    lin_relu_kernel<<<GG, 64, 0, stream>>>(z0, l1W, l1b, z1, HC);
    lin_relu_kernel<<<GG, 64, 0, stream>>>(z1, l2W, l2b, z2, DENSE);
    lin3_softmax_kernel<<<1, GG, 0, stream>>>(z2, l3W, l3b, outp);
}

// Round 14
// 543.152 us; speedup vs baseline: 1.1338x; 1.0187x over previous
//
#include <hip/hip_runtime.h>

#define N_NODES 50000
#define E_EDGES 800000
#define E2 (E_EDGES + N_NODES)
#define HC 256
#define NHEAD 4
#define GG 128
#define DENSE 64
#define NCLS 2
#define BN_EPS 1e-5f
#define NEG_SLOPE 0.2f
#define NEG_BIG -1e30f

typedef __attribute__((ext_vector_type(8))) short bf16x8;
typedef __attribute__((ext_vector_type(4))) float f32x4;

__device__ __forceinline__ unsigned short f2bf(float f) {
    unsigned int u = __float_as_uint(f);
    u = (u + 0x7FFFu + ((u >> 16) & 1u)) >> 16;
    return (unsigned short)u;
}
__device__ __forceinline__ float bf2f(unsigned short h) {
    return __uint_as_float(((unsigned int)h) << 16);
}
__device__ __forceinline__ float lrelu(float e) {
    return (e >= 0.f) ? e : NEG_SLOPE * e;
}
// accumulate 8 bf16 (packed in uint4) * w into acc[8]; lo=shift, hi=mask (no cvt)
__device__ __forceinline__ void accum8(float acc[8], uint4 v, float w) {
    acc[0] = fmaf(w, __uint_as_float(v.x << 16), acc[0]);
    acc[1] = fmaf(w, __uint_as_float(v.x & 0xffff0000u), acc[1]);
    acc[2] = fmaf(w, __uint_as_float(v.y << 16), acc[2]);
    acc[3] = fmaf(w, __uint_as_float(v.y & 0xffff0000u), acc[3]);
    acc[4] = fmaf(w, __uint_as_float(v.z << 16), acc[4]);
    acc[5] = fmaf(w, __uint_as_float(v.z & 0xffff0000u), acc[5]);
    acc[6] = fmaf(w, __uint_as_float(v.w << 16), acc[6]);
    acc[7] = fmaf(w, __uint_as_float(v.w & 0xffff0000u), acc[7]);
}

// ---------------- pack 3x W [256,256] fp32 into MFMA b-fragment order, bf16 ----------------
__global__ __launch_bounds__(64) void pack_b_kernel(const float* __restrict__ W1,
                                                    const float* __restrict__ Wl,
                                                    unsigned short* __restrict__ Bpk) {
    int l = threadIdx.x;
    int mat = blockIdx.x >> 7;          // 0..2
    int g = blockIdx.x & 127;           // ks*16+ct
    const float* W = (mat == 0) ? W1 : Wl + (size_t)(mat - 1) * HC * HC;
    int ks = g >> 4, ct = g & 15;
    int col = ct * 16 + (l & 15);
    int k0 = ks * 32 + (l >> 4) * 8;
    unsigned short v[8];
#pragma unroll
    for (int j = 0; j < 8; ++j) v[j] = f2bf(W[(size_t)(k0 + j) * HC + col]);
    ushort4* q = reinterpret_cast<ushort4*>(Bpk + ((size_t)mat * 128 * 512) + ((size_t)g * 64 + l) * 8);
    q[0] = make_ushort4(v[0], v[1], v[2], v[3]);
    q[1] = make_ushort4(v[4], v[5], v[6], v[7]);
}

// ---------------- MFMA GEMM: 128-row block, wave = 4 col-tiles x 128 rows ----------------
#define GBM 128
__global__ __launch_bounds__(256) void gemm_mfma_kernel(const unsigned short* __restrict__ A,
                                                        const float* __restrict__ A32,
                                                        const unsigned short* __restrict__ Bpk,
                                                        const float* __restrict__ prm,
                                                        unsigned short* __restrict__ C, int M) {
    __shared__ unsigned short As[GBM * 256];  // 64 KB, XOR-swizzled rows
    int tid = threadIdx.x;
    int lane = tid & 63, wid = tid >> 6;
    int row0 = blockIdx.x * GBM;
#pragma unroll
    for (int i = 0; i < 16; ++i) {
        int idx = tid + i * 256;
        int row = idx >> 5, c16 = idx & 31;
        int grow = row0 + row;
        uint4 v = make_uint4(0u, 0u, 0u, 0u);
        if (A32) {
            if (grow < M) {
                const float4* p = reinterpret_cast<const float4*>(A32 + (size_t)grow * HC + c16 * 8);
                float4 a = p[0], b = p[1];
                v.x = (unsigned int)f2bf(a.x) | ((unsigned int)f2bf(a.y) << 16);
                v.y = (unsigned int)f2bf(a.z) | ((unsigned int)f2bf(a.w) << 16);
                v.z = (unsigned int)f2bf(b.x) | ((unsigned int)f2bf(b.y) << 16);
                v.w = (unsigned int)f2bf(b.z) | ((unsigned int)f2bf(b.w) << 16);
            }
        } else {
            if (grow < M) v = *reinterpret_cast<const uint4*>(A + (size_t)grow * HC + c16 * 8);
            if (prm) {
                int ch = c16 * 8;
                const float4 s0 = *reinterpret_cast<const float4*>(prm + ch);
                const float4 s1 = *reinterpret_cast<const float4*>(prm + ch + 4);
                const float4 t0 = *reinterpret_cast<const float4*>(prm + HC + ch);
                const float4 t1 = *reinterpret_cast<const float4*>(prm + HC + ch + 4);
                float f0 = fmaxf(fmaf(__uint_as_float(v.x << 16),          s0.x, t0.x), 0.f);
                float f1 = fmaxf(fmaf(__uint_as_float(v.x & 0xffff0000u),  s0.y, t0.y), 0.f);
                float f2 = fmaxf(fmaf(__uint_as_float(v.y << 16),          s0.z, t0.z), 0.f);
                float f3 = fmaxf(fmaf(__uint_as_float(v.y & 0xffff0000u),  s0.w, t0.w), 0.f);
                float f4 = fmaxf(fmaf(__uint_as_float(v.z << 16),          s1.x, t1.x), 0.f);
                float f5 = fmaxf(fmaf(__uint_as_float(v.z & 0xffff0000u),  s1.y, t1.y), 0.f);
                float f6 = fmaxf(fmaf(__uint_as_float(v.w << 16),          s1.z, t1.z), 0.f);
                float f7 = fmaxf(fmaf(__uint_as_float(v.w & 0xffff0000u),  s1.w, t1.w), 0.f);
                v.x = (unsigned int)f2bf(f0) | ((unsigned int)f2bf(f1) << 16);
                v.y = (unsigned int)f2bf(f2) | ((unsigned int)f2bf(f3) << 16);
                v.z = (unsigned int)f2bf(f4) | ((unsigned int)f2bf(f5) << 16);
                v.w = (unsigned int)f2bf(f6) | ((unsigned int)f2bf(f7) << 16);
            }
        }
        int byteoff = row * 512 + c16 * 16;
        byteoff ^= (row & 7) << 4;
        *reinterpret_cast<uint4*>((char*)As + byteoff) = v;
    }
    __syncthreads();

    // acc[rt][c]: row-tile rt (16 rows each, 8 tiles = 128 rows), col-tile c of this wave
    f32x4 acc[8][4];
#pragma unroll
    for (int rt = 0; rt < 8; ++rt)
#pragma unroll
        for (int c = 0; c < 4; ++c) acc[rt][c] = (f32x4){0.f, 0.f, 0.f, 0.f};

    int arow = lane & 15;
    int asub = (lane >> 4) * 16;
#pragma unroll
    for (int ks = 0; ks < 8; ++ks) {
        // this wave's 4 B-frags for k-slice ks (col tiles wid*4 .. wid*4+3)
        const unsigned short* bp = Bpk + ((size_t)(ks * 16 + wid * 4) * 512 + lane * 8);
        bf16x8 b0 = *reinterpret_cast<const bf16x8*>(bp);
        bf16x8 b1 = *reinterpret_cast<const bf16x8*>(bp + 512);
        bf16x8 b2 = *reinterpret_cast<const bf16x8*>(bp + 1024);
        bf16x8 b3 = *reinterpret_cast<const bf16x8*>(bp + 1536);
#pragma unroll
        for (int rt = 0; rt < 8; ++rt) {
            int mrow = rt * 16 + arow;
            int abyte = mrow * 512 + ks * 64 + asub;
            abyte ^= (mrow & 7) << 4;
            bf16x8 a = *reinterpret_cast<const bf16x8*>((char*)As + abyte);
            acc[rt][0] = __builtin_amdgcn_mfma_f32_16x16x32_bf16(a, b0, acc[rt][0], 0, 0, 0);
            acc[rt][1] = __builtin_amdgcn_mfma_f32_16x16x32_bf16(a, b1, acc[rt][1], 0, 0, 0);
            acc[rt][2] = __builtin_amdgcn_mfma_f32_16x16x32_bf16(a, b2, acc[rt][2], 0, 0, 0);
            acc[rt][3] = __builtin_amdgcn_mfma_f32_16x16x32_bf16(a, b3, acc[rt][3], 0, 0, 0);
        }
    }
    // C/D layout: col = lane&15, row = (lane>>4)*4 + r
    int ccol = lane & 15;
#pragma unroll
    for (int rt = 0; rt < 8; ++rt) {
        int crow0 = row0 + rt * 16 + (lane >> 4) * 4;
#pragma unroll
        for (int c = 0; c < 4; ++c) {
            int gcol = (wid * 4 + c) * 16 + ccol;
#pragma unroll
            for (int r = 0; r < 4; ++r) {
                int grow = crow0 + r;
                if (grow < M) C[(size_t)grow * HC + gcol] = f2bf(acc[rt][c][r]);
            }
        }
    }
}

// ---------------- attention coefficients es/ed per node (bf16 h) ----------------
__global__ __launch_bounds__(256) void esed_kernel(const unsigned short* __restrict__ h,
                                                   const float* __restrict__ avs,
                                                   const float* __restrict__ avd,
                                                   float* __restrict__ es, float* __restrict__ ed) {
    int tid = threadIdx.x;
    int lane = tid & 63, wid = tid >> 6;
    int node = blockIdx.x * 4 + wid;
    if (node >= N_NODES) return;
    int ch0 = lane * 4;
    ushort4 hv = *reinterpret_cast<const ushort4*>(h + (size_t)node * HC + ch0);
    float4 sa = *reinterpret_cast<const float4*>(avs + ch0);
    float4 da = *reinterpret_cast<const float4*>(avd + ch0);
    float h0 = bf2f(hv.x), h1 = bf2f(hv.y), h2 = bf2f(hv.z), h3 = bf2f(hv.w);
    float vs = h0 * sa.x + h1 * sa.y + h2 * sa.z + h3 * sa.w;
    float vd = h0 * da.x + h1 * da.y + h2 * da.z + h3 * da.w;
#pragma unroll
    for (int m = 1; m < 16; m <<= 1) {
        vs += __shfl_xor(vs, m, 64);
        vd += __shfl_xor(vd, m, 64);
    }
    if ((lane & 15) == 0) {
        es[node * NHEAD + (lane >> 4)] = vs;
        ed[node * NHEAD + (lane >> 4)] = vd;
    }
}

// ---------------- CSR build ----------------
__global__ void init_deg_kernel(int* __restrict__ deg) {
    int i = blockIdx.x * blockDim.x + threadIdx.x;
    if (i < N_NODES) deg[i] = 1;  // self loop
}
__global__ void count_edges_kernel(const int* __restrict__ dst, int* __restrict__ deg) {
    int i = blockIdx.x * blockDim.x + threadIdx.x;
    if (i < E_EDGES) atomicAdd(&deg[dst[i]], 1);
}
__global__ __launch_bounds__(1024) void scan1_kernel(const int* __restrict__ deg,
                                                     int* __restrict__ rs, int* __restrict__ bsum) {
    __shared__ int wsum[16];
    int t = threadIdx.x, lane = t & 63, wid = t >> 6;
    int i = blockIdx.x * 1024 + t;
    int v = (i < N_NODES) ? deg[i] : 0;
    int x = v;
#pragma unroll
    for (int off = 1; off < 64; off <<= 1) {
        int y = __shfl_up(x, off, 64);
        if (lane >= off) x += y;
    }
    if (lane == 63) wsum[wid] = x;
    __syncthreads();
    if (wid == 0) {
        int s = (lane < 16) ? wsum[lane] : 0;
#pragma unroll
        for (int off = 1; off < 16; off <<= 1) {
            int y = __shfl_up(s, off, 64);
            if (lane >= off) s += y;
        }
        if (lane < 16) wsum[lane] = s;
    }
    __syncthreads();
    int woff = wid ? wsum[wid - 1] : 0;
    if (i <= N_NODES) rs[i] = woff + x - v;
    if (t == 1023) bsum[blockIdx.x] = wsum[15];
}
__global__ void scan2_kernel(int* __restrict__ bsum, int nb) {
    int l = threadIdx.x;
    int v = (l < nb) ? bsum[l] : 0;
    int x = v;
#pragma unroll
    for (int off = 1; off < 64; off <<= 1) {
        int y = __shfl_up(x, off, 64);
        if (l >= off) x += y;
    }
    if (l < nb) bsum[l] = x - v;
}
// scan3 + self-loop scatter fused: csr[v] = i (self loop first), cursor = v+1
__global__ void scan3_kernel(int* __restrict__ rs, const int* __restrict__ bsum,
                             int* __restrict__ cursor, int* __restrict__ csr) {
    int i = blockIdx.x * blockDim.x + threadIdx.x;
    if (i <= N_NODES) {
        int v = rs[i] + bsum[i >> 10];
        rs[i] = v;
        if (i < N_NODES) {
            csr[v] = i;
            cursor[i] = v + 1;
        }
    }
}
__global__ void scatter_edges_kernel(const int* __restrict__ src, const int* __restrict__ dst,
                                     int* __restrict__ cursor, int* __restrict__ csr) {
    int i = blockIdx.x * blockDim.x + threadIdx.x;
    if (i < E_EDGES) {
        int pos = atomicAdd(&cursor[dst[i]], 1);
        csr[pos] = src[i];
    }
}

// ---------------- softmax prep: (m,s) pass stashes e; rescale pass is streaming ----------------
__global__ __launch_bounds__(256) void smprep_kernel(const float* __restrict__ es,
                                                     const float* __restrict__ ed,
                                                     const int* __restrict__ rs,
                                                     const int* __restrict__ csr,
                                                     float* __restrict__ alpha) {
    int tid = threadIdx.x;
    int lane = tid & 63, wid = tid >> 6;
    int node = blockIdx.x * 4 + wid;
    if (node >= N_NODES) return;
    int head = lane >> 4, slot = lane & 15;
    float edn = ed[node * NHEAD + head];
    int beg = rs[node], end = rs[node + 1];
    // finite sentinel: -inf would produce NaN on empty-slot merges (deg<16 common)
    float m = NEG_BIG, s = 0.f;
    for (int i = beg + slot; i < end; i += 16) {
        float e = lrelu(es[csr[i] * NHEAD + head] + edn);
        alpha[(size_t)i * NHEAD + head] = e;   // stash for pass 2 (coalesced)
        float mn = fmaxf(m, e);
        s = s * __expf(m - mn) + __expf(e - mn);
        m = mn;
    }
#pragma unroll
    for (int off = 1; off < 16; off <<= 1) {  // merge within head group (low 4 bits)
        float mo = __shfl_xor(m, off, 64);
        float so = __shfl_xor(s, off, 64);
        float mn = fmaxf(m, mo);
        s = s * __expf(m - mn) + so * __expf(mo - mn);
        m = mn;
    }
    float inv = 1.f / (s + 1e-16f);
    for (int i = beg + slot; i < end; i += 16) {
        float e = alpha[(size_t)i * NHEAD + head];
        alpha[(size_t)i * NHEAD + head] = __expf(e - m) * inv;
    }
}

// ---------------- GAT aggregation: 2 nodes/wave, 16B/lane, unroll 4 ----------------
__global__ __launch_bounds__(256) void gat_agg_kernel(const unsigned short* __restrict__ hlin,
                                                      const float* __restrict__ alpha,
                                                      const int* __restrict__ rs,
                                                      const int* __restrict__ csr,
                                                      const float* __restrict__ bias,
                                                      unsigned short* __restrict__ out, int do_relu) {
    int tid = threadIdx.x;
    int lane = tid & 63, wid = tid >> 6;
    int node = blockIdx.x * 8 + wid * 2 + (lane >> 5);
    int hl = lane & 31;
    int ch0 = hl * 8;          // 8 channels per lane (16B)
    int head = hl >> 3;
    bool valid = node < N_NODES;
    int beg = valid ? rs[node] : 0;
    int end = valid ? rs[node + 1] : 0;
    float acc[8] = {};
    int idx = beg;
    for (; idx + 4 <= end; idx += 4) {
        int s0 = csr[idx], s1 = csr[idx + 1], s2 = csr[idx + 2], s3 = csr[idx + 3];
        float p0 = alpha[(size_t)idx * NHEAD + head];
        float p1 = alpha[(size_t)(idx + 1) * NHEAD + head];
        float p2 = alpha[(size_t)(idx + 2) * NHEAD + head];
        float p3 = alpha[(size_t)(idx + 3) * NHEAD + head];
        uint4 v0 = *reinterpret_cast<const uint4*>(hlin + (size_t)s0 * HC + ch0);
        uint4 v1 = *reinterpret_cast<const uint4*>(hlin + (size_t)s1 * HC + ch0);
        uint4 v2 = *reinterpret_cast<const uint4*>(hlin + (size_t)s2 * HC + ch0);
        uint4 v3 = *reinterpret_cast<const uint4*>(hlin + (size_t)s3 * HC + ch0);
        accum8(acc, v0, p0);
        accum8(acc, v1, p1);
        accum8(acc, v2, p2);
        accum8(acc, v3, p3);
    }
    for (; idx < end; ++idx) {
        int s0 = csr[idx];
        float p0 = alpha[(size_t)idx * NHEAD + head];
        uint4 v0 = *reinterpret_cast<const uint4*>(hlin + (size_t)s0 * HC + ch0);
        accum8(acc, v0, p0);
    }
    if (!valid) return;
    const float4 bva = *reinterpret_cast<const float4*>(bias + ch0);
    const float4 bvb = *reinterpret_cast<const float4*>(bias + ch0 + 4);
    float o[8];
    o[0] = acc[0] + bva.x; o[1] = acc[1] + bva.y; o[2] = acc[2] + bva.z; o[3] = acc[3] + bva.w;
    o[4] = acc[4] + bvb.x; o[5] = acc[5] + bvb.y; o[6] = acc[6] + bvb.z; o[7] = acc[7] + bvb.w;
    if (do_relu) {
#pragma unroll
        for (int j = 0; j < 8; ++j) o[j] = fmaxf(o[j], 0.f);
    }
    uint4 w;
    w.x = (unsigned int)f2bf(o[0]) | ((unsigned int)f2bf(o[1]) << 16);
    w.y = (unsigned int)f2bf(o[2]) | ((unsigned int)f2bf(o[3]) << 16);
    w.z = (unsigned int)f2bf(o[4]) | ((unsigned int)f2bf(o[5]) << 16);
    w.w = (unsigned int)f2bf(o[6]) | ((unsigned int)f2bf(o[7]) << 16);
    *reinterpret_cast<uint4*>(out + (size_t)node * HC + ch0) = w;
}

// ---------------- BatchNorm stats: 8 row-threads x 32 ch-threads, 16B loads ----------------
#define BN_RPB 49
__global__ __launch_bounds__(256) void bn_stats_kernel(const unsigned short* __restrict__ x,
                                                       float* __restrict__ sums) {
    __shared__ float lds[8][512];
    int tid = threadIdx.x;
    int c = tid & 31;   // channels c*8 .. c*8+7
    int rt = tid >> 5;  // 0..7
    int r0 = blockIdx.x * BN_RPB;
    int r1 = min(N_NODES, r0 + BN_RPB);
    int ch = c * 8;
    float s[8] = {}, s2[8] = {};
    for (int r = r0 + rt; r < r1; r += 8) {
        const ushort4* p = reinterpret_cast<const ushort4*>(x + (size_t)r * HC + ch);
        ushort4 va = p[0], vb = p[1];
        unsigned short in[8] = {va.x, va.y, va.z, va.w, vb.x, vb.y, vb.z, vb.w};
#pragma unroll
        for (int j = 0; j < 8; ++j) {
            float v = bf2f(in[j]);
            s[j] += v; s2[j] += v * v;
        }
    }
#pragma unroll
    for (int j = 0; j < 8; ++j) {
        lds[rt][ch + j] = s[j];
        lds[rt][256 + ch + j] = s2[j];
    }
    __syncthreads();
#pragma unroll
    for (int e = tid; e < 512; e += 256) {
        float v = 0.f;
#pragma unroll
        for (int r = 0; r < 8; ++r) v += lds[r][e];
        atomicAdd(&sums[e], v);
    }
}
__global__ void bn_finalize_kernel(const float* __restrict__ sums, const float* __restrict__ g,
                                   const float* __restrict__ b, float* __restrict__ prm) {
    int t = threadIdx.x;  // 256
    float mean = sums[t] / (float)N_NODES;
    float var = sums[HC + t] / (float)N_NODES - mean * mean;
    var = fmaxf(var, 0.f);
    float scale = g[t] * rsqrtf(var + BN_EPS);
    prm[t] = scale;
    prm[HC + t] = b[t] - mean * scale;
}

// ---------------- pooling (fused BN affine + ReLU on h2) ----------------
#define POOL_RPB 32
__global__ __launch_bounds__(256) void pool_kernel(const unsigned short* __restrict__ h,
                                                   const float* __restrict__ prm,
                                                   const int* __restrict__ batch,
                                                   float* __restrict__ psum) {
    int tid = threadIdx.x;
    int ct = tid & 63;   // channels ct*4 .. ct*4+3
    int rt = tid >> 6;   // 0..3
    int r0 = blockIdx.x * POOL_RPB;
    int r1 = min(N_NODES, r0 + POOL_RPB);
    int ch = ct * 4;
    const float4 sc = *reinterpret_cast<const float4*>(prm + ch);
    const float4 sh = *reinterpret_cast<const float4*>(prm + HC + ch);
    float a0 = 0.f, a1 = 0.f, a2 = 0.f, a3 = 0.f;
    int gcur = -1;
    for (int r = r0 + rt; r < r1; r += 4) {
        int g = batch[r];
        if (g != gcur) {
            if (gcur >= 0) {
                atomicAdd(&psum[gcur * HC + ch + 0], a0);
                atomicAdd(&psum[gcur * HC + ch + 1], a1);
                atomicAdd(&psum[gcur * HC + ch + 2], a2);
                atomicAdd(&psum[gcur * HC + ch + 3], a3);
            }
            a0 = a1 = a2 = a3 = 0.f; gcur = g;
        }
        ushort4 hv = *reinterpret_cast<const ushort4*>(h + (size_t)r * HC + ch);
        a0 += fmaxf(fmaf(bf2f(hv.x), sc.x, sh.x), 0.f);
        a1 += fmaxf(fmaf(bf2f(hv.y), sc.y, sh.y), 0.f);
        a2 += fmaxf(fmaf(bf2f(hv.z), sc.z, sh.z), 0.f);
        a3 += fmaxf(fmaf(bf2f(hv.w), sc.w, sh.w), 0.f);
    }
    if (gcur >= 0) {
        atomicAdd(&psum[gcur * HC + ch + 0], a0);
        atomicAdd(&psum[gcur * HC + ch + 1], a1);
        atomicAdd(&psum[gcur * HC + ch + 2], a2);
        atomicAdd(&psum[gcur * HC + ch + 3], a3);
    }
}
// pool_fin with inline binary-search counts (batch sorted)
__global__ void pool_fin_kernel(const float* __restrict__ psum, const int* __restrict__ batch,
                                float* __restrict__ pooled) {
    int g = blockIdx.x, t = threadIdx.x;
    int lo = 0, hi = N_NODES;
    while (lo < hi) { int mid = (lo + hi) >> 1; if (batch[mid] <= g) lo = mid + 1; else hi = mid; }
    int lo2 = 0, hi2 = N_NODES;
    while (lo2 < hi2) { int mid = (lo2 + hi2) >> 1; if (batch[mid] <= g - 1) lo2 = mid + 1; else hi2 = mid; }
    float cf = fmaxf((float)(lo - lo2), 1.f);
    pooled[g * HC + t] = psum[g * HC + t] / cf;
}

// ---------------- fused head: BN (per-block redundant stats) + 3 linears + softmax ----------------
__global__ __launch_bounds__(256) void head_kernel(const float* __restrict__ pooled,
                                                   const float* __restrict__ bn1g,
                                                   const float* __restrict__ bn1b,
                                                   const float* __restrict__ l1W,
                                                   const float* __restrict__ l1b,
                                                   const float* __restrict__ l2W,
                                                   const float* __restrict__ l2b,
                                                   const float* __restrict__ l3W,
                                                   const float* __restrict__ l3b,
                                                   float* __restrict__ out) {
    __shared__ float z0[HC];
    __shared__ float z1[DENSE];
    __shared__ float z2[DENSE];
    int r = blockIdx.x;   // graph row
    int t = threadIdx.x;  // channel
    // per-channel BN stats over 128 rows (redundant per block; coalesced, L2-hot)
    float s = 0.f, s2 = 0.f;
    for (int rr = 0; rr < GG; ++rr) {
        float v = pooled[rr * HC + t];
        s += v; s2 += v * v;
    }
    float mean = s / (float)GG;
    float var = fmaxf(s2 / (float)GG - mean * mean, 0.f);
    float scale = bn1g[t] * rsqrtf(var + BN_EPS);
    float shift = bn1b[t] - mean * scale;
    z0[t] = pooled[r * HC + t] * scale + shift;
    __syncthreads();
    if (t < DENSE) {
        float a = l1b[t];
        for (int k = 0; k < HC; ++k) a += z0[k] * l1W[k * DENSE + t];
        z1[t] = fmaxf(a, 0.f);
    }
    __syncthreads();
    if (t < DENSE) {
        float a = l2b[t];
        for (int k = 0; k < DENSE; ++k) a += z1[k] * l2W[k * DENSE + t];
        z2[t] = fmaxf(a, 0.f);
    }
    __syncthreads();
    if (t == 0) {
        float o0 = l3b[0], o1 = l3b[1];
        for (int k = 0; k < DENSE; ++k) {
            o0 += z2[k] * l3W[k * NCLS + 0];
            o1 += z2[k] * l3W[k * NCLS + 1];
        }
        o0 = fmaxf(o0, 0.f); o1 = fmaxf(o1, 0.f);
        float mx = fmaxf(o0, o1);
        float e0 = __expf(o0 - mx), e1 = __expf(o1 - mx);
        float inv = 1.f / (e0 + e1);
        out[r * NCLS + 0] = e0 * inv;
        out[r * NCLS + 1] = e1 * inv;
    }
}

extern "C" void kernel_launch(void* const* d_in, const int* in_sizes, int n_in,
                              void* d_out, int out_size, void* d_ws, size_t ws_size,
                              hipStream_t stream) {
    const float* x     = (const float*)d_in[0];
    const int*   ei    = (const int*)d_in[1];
    const int*   srcp  = ei;
    const int*   dstp  = ei + E_EDGES;
    const int*   batch = (const int*)d_in[2];
    const float* W1    = (const float*)d_in[3];
    const float* as1   = (const float*)d_in[4];
    const float* ad1   = (const float*)d_in[5];
    const float* b1    = (const float*)d_in[6];
    const float* Wl    = (const float*)d_in[7];
    const float* asl   = (const float*)d_in[8];
    const float* adl   = (const float*)d_in[9];
    const float* bl    = (const float*)d_in[10];
    const float* bng   = (const float*)d_in[11];
    const float* bnb   = (const float*)d_in[12];
    const float* bn1g  = (const float*)d_in[13];
    const float* bn1b  = (const float*)d_in[14];
    const float* l1W   = (const float*)d_in[15];
    const float* l1b   = (const float*)d_in[16];
    const float* l2W   = (const float*)d_in[17];
    const float* l2b   = (const float*)d_in[18];
    const float* l3W   = (const float*)d_in[19];
    const float* l3b   = (const float*)d_in[20];

    float* outp   = (float*)d_out;            // [128,2]
    float* pooled = outp + GG * NCLS;         // [128,256]

    char* w = (char*)d_ws;
    auto alloc = [&](size_t bytes) -> void* {
        void* p = (void*)w;
        w += (bytes + 255) & ~(size_t)255;
        return p;
    };
    unsigned short* h0  = (unsigned short*)alloc(sizeof(short) * (size_t)N_NODES * HC);
    unsigned short* h1  = (unsigned short*)alloc(sizeof(short) * (size_t)N_NODES * HC);
    unsigned short* h2  = (unsigned short*)alloc(sizeof(short) * (size_t)N_NODES * HC);
    unsigned short* Bpk = (unsigned short*)alloc(sizeof(short) * 3 * 128 * 64 * 8);
    float* es     = (float*)alloc(sizeof(float) * (size_t)N_NODES * NHEAD);
    float* ed     = (float*)alloc(sizeof(float) * (size_t)N_NODES * NHEAD);
    float* alpha  = (float*)alloc(sizeof(float) * (size_t)E2 * NHEAD);
    int*   rs     = (int*)alloc(sizeof(int) * (N_NODES + 1));
    int*   deg    = (int*)alloc(sizeof(int) * N_NODES);  // reused as cursor
    int*   csr    = (int*)alloc(sizeof(int) * E2);
    int*   bsum   = (int*)alloc(sizeof(int) * 64);
    float* bnsums = (float*)alloc(sizeof(float) * 2 * HC);
    float* bnprm  = (float*)alloc(sizeof(float) * 2 * HC);
    float* psum   = (float*)alloc(sizeof(float) * GG * HC);

    const int nblk_nodes = (N_NODES + 255) / 256;
    const int nblk_edges = (E_EDGES + 255) / 256;
    const int nblk_wave4 = (N_NODES + 3) / 4;
    const int nblk_wave8 = (N_NODES + 7) / 8;            // 6250 (2 nodes/wave)
    const int nscan = (N_NODES + 1023) / 1024;           // 49
    const int nblk_bn   = (N_NODES + BN_RPB - 1) / BN_RPB;     // 1021
    const int nblk_pool = (N_NODES + POOL_RPB - 1) / POOL_RPB; // 1563

    // ---- pack weights (3 matrices, one dispatch) ----
    pack_b_kernel<<<384, 64, 0, stream>>>(W1, Wl, Bpk);

    // ---- CSR build ----
    init_deg_kernel<<<nblk_nodes, 256, 0, stream>>>(deg);
    count_edges_kernel<<<nblk_edges, 256, 0, stream>>>(dstp, deg);
    scan1_kernel<<<nscan, 1024, 0, stream>>>(deg, rs, bsum);
    scan2_kernel<<<1, 64, 0, stream>>>(bsum, nscan);
    scan3_kernel<<<(N_NODES + 256) / 256, 256, 0, stream>>>(rs, bsum, deg, csr);
    scatter_edges_kernel<<<nblk_edges, 256, 0, stream>>>(srcp, dstp, deg, csr);

    const int ggrid = (N_NODES + GBM - 1) / GBM;   // 391

    // ---- layer 1: gemm reads fp32 x directly; h0 = relu(gat(x)) ----
    gemm_mfma_kernel<<<ggrid, 256, 0, stream>>>(nullptr, x, Bpk, nullptr, h1, N_NODES);
    esed_kernel<<<nblk_wave4, 256, 0, stream>>>(h1, as1, ad1, es, ed);
    smprep_kernel<<<nblk_wave4, 256, 0, stream>>>(es, ed, rs, csr, alpha);
    gat_agg_kernel<<<nblk_wave8, 256, 0, stream>>>(h1, alpha, rs, csr, b1, h0, 1);

    // ---- inner layer 0 ----
    gemm_mfma_kernel<<<ggrid, 256, 0, stream>>>(h0, nullptr, Bpk + 128 * 512, nullptr, h1, N_NODES);
    esed_kernel<<<nblk_wave4, 256, 0, stream>>>(h1, asl, adl, es, ed);
    smprep_kernel<<<nblk_wave4, 256, 0, stream>>>(es, ed, rs, csr, alpha);
    gat_agg_kernel<<<nblk_wave8, 256, 0, stream>>>(h1, alpha, rs, csr, bl, h2, 0);
    hipMemsetAsync(bnsums, 0, sizeof(float) * 2 * HC, stream);
    bn_stats_kernel<<<nblk_bn, 256, 0, stream>>>(h2, bnsums);
    bn_finalize_kernel<<<1, 256, 0, stream>>>(bnsums, bng, bnb, bnprm);

    // ---- inner layer 1: gemm reads h2 with fused BN0 affine+relu ----
    gemm_mfma_kernel<<<ggrid, 256, 0, stream>>>(h2, nullptr, Bpk + 2 * 128 * 512, bnprm, h1, N_NODES);
    esed_kernel<<<nblk_wave4, 256, 0, stream>>>(h1, asl + HC, adl + HC, es, ed);
    smprep_kernel<<<nblk_wave4, 256, 0, stream>>>(es, ed, rs, csr, alpha);
    gat_agg_kernel<<<nblk_wave8, 256, 0, stream>>>(h1, alpha, rs, csr, bl + HC, h2, 0);
    hipMemsetAsync(bnsums, 0, sizeof(float) * 2 * HC, stream);
    bn_stats_kernel<<<nblk_bn, 256, 0, stream>>>(h2, bnsums);
    bn_finalize_kernel<<<1, 256, 0, stream>>>(bnsums, bng + HC, bnb + HC, bnprm);

    // ---- pooling (fused BN1 affine+relu) ----
    hipMemsetAsync(psum, 0, sizeof(float) * GG * HC, stream);
    pool_kernel<<<nblk_pool, 256, 0, stream>>>(h2, bnprm, batch, psum);
    pool_fin_kernel<<<GG, HC, 0, stream>>>(psum, batch, pooled);

    // ---- fused head ----
    head_kernel<<<GG, 256, 0, stream>>>(pooled, bn1g, bn1b, l1W, l1b, l2W, l2b, l3W, l3b, outp);
}

// Round 15
// 540.575 us; speedup vs baseline: 1.1392x; 1.0048x over previous
//
#include <hip/hip_runtime.h>

#define N_NODES 50000
#define E_EDGES 800000
#define E2 (E_EDGES + N_NODES)
#define HC 256
#define NHEAD 4
#define GG 128
#define DENSE 64
#define NCLS 2
#define BN_EPS 1e-5f
#define NEG_SLOPE 0.2f
#define NEG_BIG -1e30f

typedef __attribute__((ext_vector_type(8))) short bf16x8;
typedef __attribute__((ext_vector_type(4))) float f32x4;

__device__ __forceinline__ unsigned short f2bf(float f) {
    unsigned int u = __float_as_uint(f);
    u = (u + 0x7FFFu + ((u >> 16) & 1u)) >> 16;
    return (unsigned short)u;
}
__device__ __forceinline__ float bf2f(unsigned short h) {
    return __uint_as_float(((unsigned int)h) << 16);
}
__device__ __forceinline__ float lrelu(float e) {
    return (e >= 0.f) ? e : NEG_SLOPE * e;
}
// accumulate 8 bf16 (packed in uint4) * w into acc[8]; lo=shift, hi=mask (no cvt)
__device__ __forceinline__ void accum8(float acc[8], uint4 v, float w) {
    acc[0] = fmaf(w, __uint_as_float(v.x << 16), acc[0]);
    acc[1] = fmaf(w, __uint_as_float(v.x & 0xffff0000u), acc[1]);
    acc[2] = fmaf(w, __uint_as_float(v.y << 16), acc[2]);
    acc[3] = fmaf(w, __uint_as_float(v.y & 0xffff0000u), acc[3]);
    acc[4] = fmaf(w, __uint_as_float(v.z << 16), acc[4]);
    acc[5] = fmaf(w, __uint_as_float(v.z & 0xffff0000u), acc[5]);
    acc[6] = fmaf(w, __uint_as_float(v.w << 16), acc[6]);
    acc[7] = fmaf(w, __uint_as_float(v.w & 0xffff0000u), acc[7]);
}

// ---------------- pack 3x W [256,256] fp32 into MFMA b-fragment order, bf16 ----------------
__global__ __launch_bounds__(64) void pack_b_kernel(const float* __restrict__ W1,
                                                    const float* __restrict__ Wl,
                                                    unsigned short* __restrict__ Bpk) {
    int l = threadIdx.x;
    int mat = blockIdx.x >> 7;          // 0..2
    int g = blockIdx.x & 127;           // ks*16+ct
    const float* W = (mat == 0) ? W1 : Wl + (size_t)(mat - 1) * HC * HC;
    int ks = g >> 4, ct = g & 15;
    int col = ct * 16 + (l & 15);
    int k0 = ks * 32 + (l >> 4) * 8;
    unsigned short v[8];
#pragma unroll
    for (int j = 0; j < 8; ++j) v[j] = f2bf(W[(size_t)(k0 + j) * HC + col]);
    ushort4* q = reinterpret_cast<ushort4*>(Bpk + ((size_t)mat * 128 * 512) + ((size_t)g * 64 + l) * 8);
    q[0] = make_ushort4(v[0], v[1], v[2], v[3]);
    q[1] = make_ushort4(v[4], v[5], v[6], v[7]);
}

// ---------------- MFMA GEMM: 128-row block, wave = 4 col-tiles x 128 rows ----------------
#define GBM 128
__global__ __launch_bounds__(256) void gemm_mfma_kernel(const unsigned short* __restrict__ A,
                                                        const float* __restrict__ A32,
                                                        const unsigned short* __restrict__ Bpk,
                                                        const float* __restrict__ prm,
                                                        unsigned short* __restrict__ C, int M) {
    __shared__ unsigned short As[GBM * 256];  // 64 KB, XOR-swizzled rows
    int tid = threadIdx.x;
    int lane = tid & 63, wid = tid >> 6;
    int row0 = blockIdx.x * GBM;
#pragma unroll
    for (int i = 0; i < 16; ++i) {
        int idx = tid + i * 256;
        int row = idx >> 5, c16 = idx & 31;
        int grow = row0 + row;
        uint4 v = make_uint4(0u, 0u, 0u, 0u);
        if (A32) {
            if (grow < M) {
                const float4* p = reinterpret_cast<const float4*>(A32 + (size_t)grow * HC + c16 * 8);
                float4 a = p[0], b = p[1];
                v.x = (unsigned int)f2bf(a.x) | ((unsigned int)f2bf(a.y) << 16);
                v.y = (unsigned int)f2bf(a.z) | ((unsigned int)f2bf(a.w) << 16);
                v.z = (unsigned int)f2bf(b.x) | ((unsigned int)f2bf(b.y) << 16);
                v.w = (unsigned int)f2bf(b.z) | ((unsigned int)f2bf(b.w) << 16);
            }
        } else {
            if (grow < M) v = *reinterpret_cast<const uint4*>(A + (size_t)grow * HC + c16 * 8);
            if (prm) {
                int ch = c16 * 8;
                const float4 s0 = *reinterpret_cast<const float4*>(prm + ch);
                const float4 s1 = *reinterpret_cast<const float4*>(prm + ch + 4);
                const float4 t0 = *reinterpret_cast<const float4*>(prm + HC + ch);
                const float4 t1 = *reinterpret_cast<const float4*>(prm + HC + ch + 4);
                float f0 = fmaxf(fmaf(__uint_as_float(v.x << 16),          s0.x, t0.x), 0.f);
                float f1 = fmaxf(fmaf(__uint_as_float(v.x & 0xffff0000u),  s0.y, t0.y), 0.f);
                float f2 = fmaxf(fmaf(__uint_as_float(v.y << 16),          s0.z, t0.z), 0.f);
                float f3 = fmaxf(fmaf(__uint_as_float(v.y & 0xffff0000u),  s0.w, t0.w), 0.f);
                float f4 = fmaxf(fmaf(__uint_as_float(v.z << 16),          s1.x, t1.x), 0.f);
                float f5 = fmaxf(fmaf(__uint_as_float(v.z & 0xffff0000u),  s1.y, t1.y), 0.f);
                float f6 = fmaxf(fmaf(__uint_as_float(v.w << 16),          s1.z, t1.z), 0.f);
                float f7 = fmaxf(fmaf(__uint_as_float(v.w & 0xffff0000u),  s1.w, t1.w), 0.f);
                v.x = (unsigned int)f2bf(f0) | ((unsigned int)f2bf(f1) << 16);
                v.y = (unsigned int)f2bf(f2) | ((unsigned int)f2bf(f3) << 16);
                v.z = (unsigned int)f2bf(f4) | ((unsigned int)f2bf(f5) << 16);
                v.w = (unsigned int)f2bf(f6) | ((unsigned int)f2bf(f7) << 16);
            }
        }
        int byteoff = row * 512 + c16 * 16;
        byteoff ^= (row & 7) << 4;
        *reinterpret_cast<uint4*>((char*)As + byteoff) = v;
    }
    __syncthreads();

    f32x4 acc[8][4];
#pragma unroll
    for (int rt = 0; rt < 8; ++rt)
#pragma unroll
        for (int c = 0; c < 4; ++c) acc[rt][c] = (f32x4){0.f, 0.f, 0.f, 0.f};

    int arow = lane & 15;
    int asub = (lane >> 4) * 16;
#pragma unroll
    for (int ks = 0; ks < 8; ++ks) {
        const unsigned short* bp = Bpk + ((size_t)(ks * 16 + wid * 4) * 512 + lane * 8);
        bf16x8 b0 = *reinterpret_cast<const bf16x8*>(bp);
        bf16x8 b1 = *reinterpret_cast<const bf16x8*>(bp + 512);
        bf16x8 b2 = *reinterpret_cast<const bf16x8*>(bp + 1024);
        bf16x8 b3 = *reinterpret_cast<const bf16x8*>(bp + 1536);
#pragma unroll
        for (int rt = 0; rt < 8; ++rt) {
            int mrow = rt * 16 + arow;
            int abyte = mrow * 512 + ks * 64 + asub;
            abyte ^= (mrow & 7) << 4;
            bf16x8 a = *reinterpret_cast<const bf16x8*>((char*)As + abyte);
            acc[rt][0] = __builtin_amdgcn_mfma_f32_16x16x32_bf16(a, b0, acc[rt][0], 0, 0, 0);
            acc[rt][1] = __builtin_amdgcn_mfma_f32_16x16x32_bf16(a, b1, acc[rt][1], 0, 0, 0);
            acc[rt][2] = __builtin_amdgcn_mfma_f32_16x16x32_bf16(a, b2, acc[rt][2], 0, 0, 0);
            acc[rt][3] = __builtin_amdgcn_mfma_f32_16x16x32_bf16(a, b3, acc[rt][3], 0, 0, 0);
        }
    }
    int ccol = lane & 15;
#pragma unroll
    for (int rt = 0; rt < 8; ++rt) {
        int crow0 = row0 + rt * 16 + (lane >> 4) * 4;
#pragma unroll
        for (int c = 0; c < 4; ++c) {
            int gcol = (wid * 4 + c) * 16 + ccol;
#pragma unroll
            for (int r = 0; r < 4; ++r) {
                int grow = crow0 + r;
                if (grow < M) C[(size_t)grow * HC + gcol] = f2bf(acc[rt][c][r]);
            }
        }
    }
}

// ---------------- attention coefficients es/ed per node (bf16 h) ----------------
__global__ __launch_bounds__(256) void esed_kernel(const unsigned short* __restrict__ h,
                                                   const float* __restrict__ avs,
                                                   const float* __restrict__ avd,
                                                   float* __restrict__ es, float* __restrict__ ed) {
    int tid = threadIdx.x;
    int lane = tid & 63, wid = tid >> 6;
    int node = blockIdx.x * 4 + wid;
    if (node >= N_NODES) return;
    int ch0 = lane * 4;
    ushort4 hv = *reinterpret_cast<const ushort4*>(h + (size_t)node * HC + ch0);
    float4 sa = *reinterpret_cast<const float4*>(avs + ch0);
    float4 da = *reinterpret_cast<const float4*>(avd + ch0);
    float h0 = bf2f(hv.x), h1 = bf2f(hv.y), h2 = bf2f(hv.z), h3 = bf2f(hv.w);
    float vs = h0 * sa.x + h1 * sa.y + h2 * sa.z + h3 * sa.w;
    float vd = h0 * da.x + h1 * da.y + h2 * da.z + h3 * da.w;
#pragma unroll
    for (int m = 1; m < 16; m <<= 1) {
        vs += __shfl_xor(vs, m, 64);
        vd += __shfl_xor(vd, m, 64);
    }
    if ((lane & 15) == 0) {
        es[node * NHEAD + (lane >> 4)] = vs;
        ed[node * NHEAD + (lane >> 4)] = vd;
    }
}

// ---------------- CSR build ----------------
__global__ void count_edges_kernel(const int* __restrict__ dst, int* __restrict__ deg) {
    int i = blockIdx.x * blockDim.x + threadIdx.x;
    if (i < E_EDGES) atomicAdd(&deg[dst[i]], 1);
}
// scan1: deg holds edge counts (no self loop); +1 applied inline
__global__ __launch_bounds__(1024) void scan1_kernel(const int* __restrict__ deg,
                                                     int* __restrict__ rs, int* __restrict__ bsum) {
    __shared__ int wsum[16];
    int t = threadIdx.x, lane = t & 63, wid = t >> 6;
    int i = blockIdx.x * 1024 + t;
    int v = (i < N_NODES) ? deg[i] + 1 : 0;
    int x = v;
#pragma unroll
    for (int off = 1; off < 64; off <<= 1) {
        int y = __shfl_up(x, off, 64);
        if (lane >= off) x += y;
    }
    if (lane == 63) wsum[wid] = x;
    __syncthreads();
    if (wid == 0) {
        int s = (lane < 16) ? wsum[lane] : 0;
#pragma unroll
        for (int off = 1; off < 16; off <<= 1) {
            int y = __shfl_up(s, off, 64);
            if (lane >= off) s += y;
        }
        if (lane < 16) wsum[lane] = s;
    }
    __syncthreads();
    int woff = wid ? wsum[wid - 1] : 0;
    if (i <= N_NODES) rs[i] = woff + x - v;
    if (t == 1023) bsum[blockIdx.x] = wsum[15];
}
// scan3 with inline bsum prefix (<=49 L2-hot ints) + fused self-loop scatter
__global__ void scan3_kernel(int* __restrict__ rs, const int* __restrict__ bsum,
                             int* __restrict__ cursor, int* __restrict__ csr) {
    int i = blockIdx.x * blockDim.x + threadIdx.x;
    if (i <= N_NODES) {
        int c = i >> 10;
        int off = 0;
        for (int k = 0; k < c; ++k) off += bsum[k];
        int v = rs[i] + off;
        rs[i] = v;
        if (i < N_NODES) {
            csr[v] = i;
            cursor[i] = v + 1;
        }
    }
}
__global__ void scatter_edges_kernel(const int* __restrict__ src, const int* __restrict__ dst,
                                     int* __restrict__ cursor, int* __restrict__ csr) {
    int i = blockIdx.x * blockDim.x + threadIdx.x;
    if (i < E_EDGES) {
        int pos = atomicAdd(&cursor[dst[i]], 1);
        csr[pos] = src[i];
    }
}

// ---------------- softmax prep: reg-cached e (deg<=64 fast path), single alpha write ----------------
__global__ __launch_bounds__(256) void smprep_kernel(const float* __restrict__ es,
                                                     const float* __restrict__ ed,
                                                     const int* __restrict__ rs,
                                                     const int* __restrict__ csr,
                                                     float* __restrict__ alpha) {
    int tid = threadIdx.x;
    int lane = tid & 63, wid = tid >> 6;
    int node = blockIdx.x * 4 + wid;
    if (node >= N_NODES) return;
    int head = lane >> 4, slot = lane & 15;
    float edn = ed[node * NHEAD + head];
    int beg = rs[node], end = rs[node + 1];
    // finite sentinel: -inf would produce NaN on empty-slot merges (deg<16 common)
    float m = NEG_BIG, s = 0.f;
    float e0c = 0.f, e1c = 0.f, e2c = 0.f, e3c = 0.f;  // reg cache (static names, rule #20)
    int cnt = 0;
    for (int i = beg + slot; i < end; i += 16) {
        float e = lrelu(es[csr[i] * NHEAD + head] + edn);
        if (cnt == 0) e0c = e; else if (cnt == 1) e1c = e;
        else if (cnt == 2) e2c = e; else if (cnt == 3) e3c = e;
        ++cnt;
        float mn = fmaxf(m, e);
        s = s * __expf(m - mn) + __expf(e - mn);
        m = mn;
    }
#pragma unroll
    for (int off = 1; off < 16; off <<= 1) {  // merge within head group (low 4 bits)
        float mo = __shfl_xor(m, off, 64);
        float so = __shfl_xor(s, off, 64);
        float mn = fmaxf(m, mo);
        s = s * __expf(m - mn) + so * __expf(mo - mn);
        m = mn;
    }
    float inv = 1.f / (s + 1e-16f);
    int k = 0;
    for (int i = beg + slot; i < end; i += 16, ++k) {
        float e;
        if (k == 0) e = e0c; else if (k == 1) e = e1c;
        else if (k == 2) e = e2c; else if (k == 3) e = e3c;
        else e = lrelu(es[csr[i] * NHEAD + head] + edn);   // rare deep-node fallback
        alpha[(size_t)i * NHEAD + head] = __expf(e - m) * inv;
    }
}

// ---------------- GAT aggregation: 2 nodes/wave, 16B/lane, unroll 4 ----------------
__global__ __launch_bounds__(256) void gat_agg_kernel(const unsigned short* __restrict__ hlin,
                                                      const float* __restrict__ alpha,
                                                      const int* __restrict__ rs,
                                                      const int* __restrict__ csr,
                                                      const float* __restrict__ bias,
                                                      unsigned short* __restrict__ out, int do_relu) {
    int tid = threadIdx.x;
    int lane = tid & 63, wid = tid >> 6;
    int node = blockIdx.x * 8 + wid * 2 + (lane >> 5);
    int hl = lane & 31;
    int ch0 = hl * 8;          // 8 channels per lane (16B)
    int head = hl >> 3;
    bool valid = node < N_NODES;
    int beg = valid ? rs[node] : 0;
    int end = valid ? rs[node + 1] : 0;
    float acc[8] = {};
    int idx = beg;
    for (; idx + 4 <= end; idx += 4) {
        int s0 = csr[idx], s1 = csr[idx + 1], s2 = csr[idx + 2], s3 = csr[idx + 3];
        float p0 = alpha[(size_t)idx * NHEAD + head];
        float p1 = alpha[(size_t)(idx + 1) * NHEAD + head];
        float p2 = alpha[(size_t)(idx + 2) * NHEAD + head];
        float p3 = alpha[(size_t)(idx + 3) * NHEAD + head];
        uint4 v0 = *reinterpret_cast<const uint4*>(hlin + (size_t)s0 * HC + ch0);
        uint4 v1 = *reinterpret_cast<const uint4*>(hlin + (size_t)s1 * HC + ch0);
        uint4 v2 = *reinterpret_cast<const uint4*>(hlin + (size_t)s2 * HC + ch0);
        uint4 v3 = *reinterpret_cast<const uint4*>(hlin + (size_t)s3 * HC + ch0);
        accum8(acc, v0, p0);
        accum8(acc, v1, p1);
        accum8(acc, v2, p2);
        accum8(acc, v3, p3);
    }
    for (; idx < end; ++idx) {
        int s0 = csr[idx];
        float p0 = alpha[(size_t)idx * NHEAD + head];
        uint4 v0 = *reinterpret_cast<const uint4*>(hlin + (size_t)s0 * HC + ch0);
        accum8(acc, v0, p0);
    }
    if (!valid) return;
    const float4 bva = *reinterpret_cast<const float4*>(bias + ch0);
    const float4 bvb = *reinterpret_cast<const float4*>(bias + ch0 + 4);
    float o[8];
    o[0] = acc[0] + bva.x; o[1] = acc[1] + bva.y; o[2] = acc[2] + bva.z; o[3] = acc[3] + bva.w;
    o[4] = acc[4] + bvb.x; o[5] = acc[5] + bvb.y; o[6] = acc[6] + bvb.z; o[7] = acc[7] + bvb.w;
    if (do_relu) {
#pragma unroll
        for (int j = 0; j < 8; ++j) o[j] = fmaxf(o[j], 0.f);
    }
    uint4 w;
    w.x = (unsigned int)f2bf(o[0]) | ((unsigned int)f2bf(o[1]) << 16);
    w.y = (unsigned int)f2bf(o[2]) | ((unsigned int)f2bf(o[3]) << 16);
    w.z = (unsigned int)f2bf(o[4]) | ((unsigned int)f2bf(o[5]) << 16);
    w.w = (unsigned int)f2bf(o[6]) | ((unsigned int)f2bf(o[7]) << 16);
    *reinterpret_cast<uint4*>(out + (size_t)node * HC + ch0) = w;
}

// ---------------- BatchNorm stats: 8 row-threads x 32 ch-threads, 16B loads ----------------
#define BN_RPB 49
__global__ __launch_bounds__(256) void bn_stats_kernel(const unsigned short* __restrict__ x,
                                                       float* __restrict__ sums) {
    __shared__ float lds[8][512];
    int tid = threadIdx.x;
    int c = tid & 31;   // channels c*8 .. c*8+7
    int rt = tid >> 5;  // 0..7
    int r0 = blockIdx.x * BN_RPB;
    int r1 = min(N_NODES, r0 + BN_RPB);
    int ch = c * 8;
    float s[8] = {}, s2[8] = {};
    for (int r = r0 + rt; r < r1; r += 8) {
        const ushort4* p = reinterpret_cast<const ushort4*>(x + (size_t)r * HC + ch);
        ushort4 va = p[0], vb = p[1];
        unsigned short in[8] = {va.x, va.y, va.z, va.w, vb.x, vb.y, vb.z, vb.w};
#pragma unroll
        for (int j = 0; j < 8; ++j) {
            float v = bf2f(in[j]);
            s[j] += v; s2[j] += v * v;
        }
    }
#pragma unroll
    for (int j = 0; j < 8; ++j) {
        lds[rt][ch + j] = s[j];
        lds[rt][256 + ch + j] = s2[j];
    }
    __syncthreads();
#pragma unroll
    for (int e = tid; e < 512; e += 256) {
        float v = 0.f;
#pragma unroll
        for (int r = 0; r < 8; ++r) v += lds[r][e];
        atomicAdd(&sums[e], v);
    }
}
__global__ void bn_finalize_kernel(const float* __restrict__ sums, const float* __restrict__ g,
                                   const float* __restrict__ b, float* __restrict__ prm) {
    int t = threadIdx.x;  // 256
    float mean = sums[t] / (float)N_NODES;
    float var = sums[HC + t] / (float)N_NODES - mean * mean;
    var = fmaxf(var, 0.f);
    float scale = g[t] * rsqrtf(var + BN_EPS);
    prm[t] = scale;
    prm[HC + t] = b[t] - mean * scale;
}

// ---------------- pooling (fused BN affine + ReLU on h2) ----------------
#define POOL_RPB 32
__global__ __launch_bounds__(256) void pool_kernel(const unsigned short* __restrict__ h,
                                                   const float* __restrict__ prm,
                                                   const int* __restrict__ batch,
                                                   float* __restrict__ psum) {
    int tid = threadIdx.x;
    int ct = tid & 63;   // channels ct*4 .. ct*4+3
    int rt = tid >> 6;   // 0..3
    int r0 = blockIdx.x * POOL_RPB;
    int r1 = min(N_NODES, r0 + POOL_RPB);
    int ch = ct * 4;
    const float4 sc = *reinterpret_cast<const float4*>(prm + ch);
    const float4 sh = *reinterpret_cast<const float4*>(prm + HC + ch);
    float a0 = 0.f, a1 = 0.f, a2 = 0.f, a3 = 0.f;
    int gcur = -1;
    for (int r = r0 + rt; r < r1; r += 4) {
        int g = batch[r];
        if (g != gcur) {
            if (gcur >= 0) {
                atomicAdd(&psum[gcur * HC + ch + 0], a0);
                atomicAdd(&psum[gcur * HC + ch + 1], a1);
                atomicAdd(&psum[gcur * HC + ch + 2], a2);
                atomicAdd(&psum[gcur * HC + ch + 3], a3);
            }
            a0 = a1 = a2 = a3 = 0.f; gcur = g;
        }
        ushort4 hv = *reinterpret_cast<const ushort4*>(h + (size_t)r * HC + ch);
        a0 += fmaxf(fmaf(bf2f(hv.x), sc.x, sh.x), 0.f);
        a1 += fmaxf(fmaf(bf2f(hv.y), sc.y, sh.y), 0.f);
        a2 += fmaxf(fmaf(bf2f(hv.z), sc.z, sh.z), 0.f);
        a3 += fmaxf(fmaf(bf2f(hv.w), sc.w, sh.w), 0.f);
    }
    if (gcur >= 0) {
        atomicAdd(&psum[gcur * HC + ch + 0], a0);
        atomicAdd(&psum[gcur * HC + ch + 1], a1);
        atomicAdd(&psum[gcur * HC + ch + 2], a2);
        atomicAdd(&psum[gcur * HC + ch + 3], a3);
    }
}

// ---------------- fused head: pool_fin + BN + 3 linears + softmax ----------------
__global__ __launch_bounds__(256) void head_kernel(const float* __restrict__ psum,
                                                   const int* __restrict__ batch,
                                                   const float* __restrict__ bn1g,
                                                   const float* __restrict__ bn1b,
                                                   const float* __restrict__ l1W,
                                                   const float* __restrict__ l1b,
                                                   const float* __restrict__ l2W,
                                                   const float* __restrict__ l2b,
                                                   const float* __restrict__ l3W,
                                                   const float* __restrict__ l3b,
                                                   float* __restrict__ pooled,
                                                   float* __restrict__ out) {
    __shared__ float invc[GG];
    __shared__ float z0[HC];
    __shared__ float z1[DENSE];
    __shared__ float z2[DENSE];
    int r = blockIdx.x;   // graph row
    int t = threadIdx.x;  // channel
    if (t < GG) {
        int g = t;
        int lo = 0, hi = N_NODES;
        while (lo < hi) { int mid = (lo + hi) >> 1; if (batch[mid] <= g) lo = mid + 1; else hi = mid; }
        int lo2 = 0, hi2 = N_NODES;
        while (lo2 < hi2) { int mid = (lo2 + hi2) >> 1; if (batch[mid] <= g - 1) lo2 = mid + 1; else hi2 = mid; }
        invc[t] = 1.f / fmaxf((float)(lo - lo2), 1.f);
    }
    __syncthreads();
    // per-channel BN stats over 128 pooled rows (psum * invc), redundant per block
    float s = 0.f, s2 = 0.f;
    for (int rr = 0; rr < GG; ++rr) {
        float v = psum[rr * HC + t] * invc[rr];
        s += v; s2 += v * v;
    }
    float pr = psum[r * HC + t] * invc[r];
    pooled[r * HC + t] = pr;                 // output 1 (block r owns row r)
    float mean = s / (float)GG;
    float var = fmaxf(s2 / (float)GG - mean * mean, 0.f);
    float scale = bn1g[t] * rsqrtf(var + BN_EPS);
    float shift = bn1b[t] - mean * scale;
    z0[t] = pr * scale + shift;
    __syncthreads();
    if (t < DENSE) {
        float a = l1b[t];
        for (int k = 0; k < HC; ++k) a += z0[k] * l1W[k * DENSE + t];
        z1[t] = fmaxf(a, 0.f);
    }
    __syncthreads();
    if (t < DENSE) {
        float a = l2b[t];
        for (int k = 0; k < DENSE; ++k) a += z1[k] * l2W[k * DENSE + t];
        z2[t] = fmaxf(a, 0.f);
    }
    __syncthreads();
    if (t == 0) {
        float o0 = l3b[0], o1 = l3b[1];
        for (int k = 0; k < DENSE; ++k) {
            o0 += z2[k] * l3W[k * NCLS + 0];
            o1 += z2[k] * l3W[k * NCLS + 1];
        }
        o0 = fmaxf(o0, 0.f); o1 = fmaxf(o1, 0.f);
        float mx = fmaxf(o0, o1);
        float e0 = __expf(o0 - mx), e1 = __expf(o1 - mx);
        float inv = 1.f / (e0 + e1);
        out[r * NCLS + 0] = e0 * inv;
        out[r * NCLS + 1] = e1 * inv;
    }
}

extern "C" void kernel_launch(void* const* d_in, const int* in_sizes, int n_in,
                              void* d_out, int out_size, void* d_ws, size_t ws_size,
                              hipStream_t stream) {
    const float* x     = (const float*)d_in[0];
    const int*   ei    = (const int*)d_in[1];
    const int*   srcp  = ei;
    const int*   dstp  = ei + E_EDGES;
    const int*   batch = (const int*)d_in[2];
    const float* W1    = (const float*)d_in[3];
    const float* as1   = (const float*)d_in[4];
    const float* ad1   = (const float*)d_in[5];
    const float* b1    = (const float*)d_in[6];
    const float* Wl    = (const float*)d_in[7];
    const float* asl   = (const float*)d_in[8];
    const float* adl   = (const float*)d_in[9];
    const float* bl    = (const float*)d_in[10];
    const float* bng   = (const float*)d_in[11];
    const float* bnb   = (const float*)d_in[12];
    const float* bn1g  = (const float*)d_in[13];
    const float* bn1b  = (const float*)d_in[14];
    const float* l1W   = (const float*)d_in[15];
    const float* l1b   = (const float*)d_in[16];
    const float* l2W   = (const float*)d_in[17];
    const float* l2b   = (const float*)d_in[18];
    const float* l3W   = (const float*)d_in[19];
    const float* l3b   = (const float*)d_in[20];

    float* outp   = (float*)d_out;            // [128,2]
    float* pooled = outp + GG * NCLS;         // [128,256]

    char* w = (char*)d_ws;
    auto alloc = [&](size_t bytes) -> void* {
        void* p = (void*)w;
        w += (bytes + 255) & ~(size_t)255;
        return p;
    };
    unsigned short* h0  = (unsigned short*)alloc(sizeof(short) * (size_t)N_NODES * HC);
    unsigned short* h1  = (unsigned short*)alloc(sizeof(short) * (size_t)N_NODES * HC);
    unsigned short* h2  = (unsigned short*)alloc(sizeof(short) * (size_t)N_NODES * HC);
    unsigned short* Bpk = (unsigned short*)alloc(sizeof(short) * 3 * 128 * 64 * 8);
    float* es     = (float*)alloc(sizeof(float) * (size_t)N_NODES * NHEAD);
    float* ed     = (float*)alloc(sizeof(float) * (size_t)N_NODES * NHEAD);
    float* alpha  = (float*)alloc(sizeof(float) * (size_t)E2 * NHEAD);
    int*   rs     = (int*)alloc(sizeof(int) * (N_NODES + 1));
    int*   deg    = (int*)alloc(sizeof(int) * N_NODES);  // reused as cursor
    int*   csr    = (int*)alloc(sizeof(int) * E2);
    int*   bsum   = (int*)alloc(sizeof(int) * 64);
    float* bnsums = (float*)alloc(sizeof(float) * 2 * HC);
    float* bnprm  = (float*)alloc(sizeof(float) * 2 * HC);
    float* psum   = (float*)alloc(sizeof(float) * GG * HC);

    const int nblk_edges = (E_EDGES + 255) / 256;
    const int nblk_wave4 = (N_NODES + 3) / 4;
    const int nblk_wave8 = (N_NODES + 7) / 8;            // 6250 (2 nodes/wave)
    const int nscan = (N_NODES + 1023) / 1024;           // 49
    const int nblk_bn   = (N_NODES + BN_RPB - 1) / BN_RPB;     // 1021
    const int nblk_pool = (N_NODES + POOL_RPB - 1) / POOL_RPB; // 1563

    // ---- pack weights (3 matrices, one dispatch) ----
    pack_b_kernel<<<384, 64, 0, stream>>>(W1, Wl, Bpk);

    // ---- CSR build ----
    hipMemsetAsync(deg, 0, sizeof(int) * N_NODES, stream);
    count_edges_kernel<<<nblk_edges, 256, 0, stream>>>(dstp, deg);
    scan1_kernel<<<nscan, 1024, 0, stream>>>(deg, rs, bsum);
    scan3_kernel<<<(N_NODES + 256) / 256, 256, 0, stream>>>(rs, bsum, deg, csr);
    scatter_edges_kernel<<<nblk_edges, 256, 0, stream>>>(srcp, dstp, deg, csr);

    const int ggrid = (N_NODES + GBM - 1) / GBM;   // 391

    // ---- layer 1: gemm reads fp32 x directly; h0 = relu(gat(x)) ----
    gemm_mfma_kernel<<<ggrid, 256, 0, stream>>>(nullptr, x, Bpk, nullptr, h1, N_NODES);
    esed_kernel<<<nblk_wave4, 256, 0, stream>>>(h1, as1, ad1, es, ed);
    smprep_kernel<<<nblk_wave4, 256, 0, stream>>>(es, ed, rs, csr, alpha);
    gat_agg_kernel<<<nblk_wave8, 256, 0, stream>>>(h1, alpha, rs, csr, b1, h0, 1);

    // ---- inner layer 0 ----
    gemm_mfma_kernel<<<ggrid, 256, 0, stream>>>(h0, nullptr, Bpk + 128 * 512, nullptr, h1, N_NODES);
    esed_kernel<<<nblk_wave4, 256, 0, stream>>>(h1, asl, adl, es, ed);
    smprep_kernel<<<nblk_wave4, 256, 0, stream>>>(es, ed, rs, csr, alpha);
    gat_agg_kernel<<<nblk_wave8, 256, 0, stream>>>(h1, alpha, rs, csr, bl, h2, 0);
    hipMemsetAsync(bnsums, 0, sizeof(float) * 2 * HC, stream);
    bn_stats_kernel<<<nblk_bn, 256, 0, stream>>>(h2, bnsums);
    bn_finalize_kernel<<<1, 256, 0, stream>>>(bnsums, bng, bnb, bnprm);

    // ---- inner layer 1: gemm reads h2 with fused BN0 affine+relu ----
    gemm_mfma_kernel<<<ggrid, 256, 0, stream>>>(h2, nullptr, Bpk + 2 * 128 * 512, bnprm, h1, N_NODES);
    esed_kernel<<<nblk_wave4, 256, 0, stream>>>(h1, asl + HC, adl + HC, es, ed);
    smprep_kernel<<<nblk_wave4, 256, 0, stream>>>(es, ed, rs, csr, alpha);
    gat_agg_kernel<<<nblk_wave8, 256, 0, stream>>>(h1, alpha, rs, csr, bl + HC, h2, 0);
    hipMemsetAsync(bnsums, 0, sizeof(float) * 2 * HC, stream);
    bn_stats_kernel<<<nblk_bn, 256, 0, stream>>>(h2, bnsums);
    bn_finalize_kernel<<<1, 256, 0, stream>>>(bnsums, bng + HC, bnb + HC, bnprm);

    // ---- pooling (fused BN1 affine+relu) ----
    hipMemsetAsync(psum, 0, sizeof(float) * GG * HC, stream);
    pool_kernel<<<nblk_pool, 256, 0, stream>>>(h2, bnprm, batch, psum);

    // ---- fused head (pool_fin + BN + MLP + softmax) ----
    head_kernel<<<GG, 256, 0, stream>>>(psum, batch, bn1g, bn1b, l1W, l1b, l2W, l2b,
                                        l3W, l3b, pooled, outp);
}